// Round 1
// baseline (3086.413 us; speedup 1.0000x reference)
//
#include <hip/hip_runtime.h>

#define INF30 1e30f
#define INV_TAU 0.08838834764831845f

__device__ __forceinline__ float4 ld4(const float* p) { return *(const float4*)p; }

// ---------------- LayerNorm over DM=1024 (no affine) ----------------
__global__ __launch_bounds__(256) void ln_dm_kernel(const float* __restrict__ x, float* __restrict__ y) {
    size_t row = blockIdx.x;
    const float4* xr = (const float4*)(x + row * 1024);
    float4 v = xr[threadIdx.x];
    float s  = v.x + v.y + v.z + v.w;
    float ss = v.x*v.x + v.y*v.y + v.z*v.z + v.w*v.w;
#pragma unroll
    for (int off = 32; off > 0; off >>= 1) {
        s  += __shfl_down(s, off);
        ss += __shfl_down(ss, off);
    }
    __shared__ float rs[4], rss[4];
    int wv = threadIdx.x >> 6, ln = threadIdx.x & 63;
    if (ln == 0) { rs[wv] = s; rss[wv] = ss; }
    __syncthreads();
    s  = rs[0] + rs[1] + rs[2] + rs[3];
    ss = rss[0] + rss[1] + rss[2] + rss[3];
    float mu  = s * (1.0f/1024.0f);
    float var = ss * (1.0f/1024.0f) - mu*mu;
    float r = rsqrtf(var + 1e-6f);
    float4 o;
    o.x = (v.x - mu) * r; o.y = (v.y - mu) * r; o.z = (v.z - mu) * r; o.w = (v.w - mu) * r;
    ((float4*)(y + row * 1024))[threadIdx.x] = o;
}

// ---------------- fp32 tiled GEMM: C[4096,N] = A[4096,1024] @ W[1024,N] ----------------
// mode 0: scatter to q (B,H,L,128)
// mode 1: cols [0,1024) -> k, [1024,2048) -> v (both (B,H,L,128)), [2048,3072) -> silu -> g (B,L,1024)
// mode 2: plain row-major write to o0 (4096,1024)
__global__ __launch_bounds__(256) void gemm_kernel(const float* __restrict__ A, const float* __restrict__ W,
                                                   int N, int mode,
                                                   float* __restrict__ o0, float* __restrict__ o1,
                                                   float* __restrict__ o2) {
    __shared__ float As[16][64];
    __shared__ float Bs[16][64];
    int t = threadIdx.x;
    int col0 = blockIdx.x << 6;
    int row0 = blockIdx.y << 6;
    int tx = t & 15, ty = t >> 4;
    int arow = t >> 2, akq = t & 3;
    int bkr = t >> 4, bcq = t & 15;
    const float* Ap = A + (size_t)(row0 + arow) * 1024 + akq * 4;
    const float* Wp = W + (size_t)bkr * N + col0 + bcq * 4;
    float acc[4][4];
#pragma unroll
    for (int i = 0; i < 4; ++i)
#pragma unroll
        for (int j = 0; j < 4; ++j) acc[i][j] = 0.0f;

    for (int kt = 0; kt < 64; ++kt) {
        float4 a4 = ld4(Ap + kt * 16);
        float4 b4 = ld4(Wp + (size_t)kt * 16 * N);
        __syncthreads();
        As[akq*4+0][arow] = a4.x;
        As[akq*4+1][arow] = a4.y;
        As[akq*4+2][arow] = a4.z;
        As[akq*4+3][arow] = a4.w;
        *(float4*)&Bs[bkr][bcq*4] = b4;
        __syncthreads();
#pragma unroll
        for (int kk = 0; kk < 16; ++kk) {
            float4 av = *(float4*)&As[kk][ty*4];
            float4 bv = *(float4*)&Bs[kk][tx*4];
            acc[0][0] += av.x*bv.x; acc[0][1] += av.x*bv.y; acc[0][2] += av.x*bv.z; acc[0][3] += av.x*bv.w;
            acc[1][0] += av.y*bv.x; acc[1][1] += av.y*bv.y; acc[1][2] += av.y*bv.z; acc[1][3] += av.y*bv.w;
            acc[2][0] += av.z*bv.x; acc[2][1] += av.z*bv.y; acc[2][2] += av.z*bv.z; acc[2][3] += av.z*bv.w;
            acc[3][0] += av.w*bv.x; acc[3][1] += av.w*bv.y; acc[3][2] += av.w*bv.z; acc[3][3] += av.w*bv.w;
        }
    }

#pragma unroll
    for (int i = 0; i < 4; ++i) {
        int rr = row0 + ty*4 + i;
        int b = rr >> 9, l = rr & 511;
#pragma unroll
        for (int j = 0; j < 4; ++j) {
            int cc = col0 + tx*4 + j;
            float vv = acc[i][j];
            if (mode == 0) {
                o0[((size_t)((b<<3) + (cc>>7)) * 512 + l) * 128 + (cc & 127)] = vv;
            } else if (mode == 1) {
                if (cc < 1024) {
                    o0[((size_t)((b<<3) + (cc>>7)) * 512 + l) * 128 + (cc & 127)] = vv;
                } else if (cc < 2048) {
                    int c2 = cc - 1024;
                    o1[((size_t)((b<<3) + (c2>>7)) * 512 + l) * 128 + (c2 & 127)] = vv;
                } else {
                    o2[(size_t)rr * 1024 + (cc - 2048)] = vv / (1.0f + __expf(-vv));
                }
            } else {
                o0[(size_t)rr * 1024 + cc] = vv;
            }
        }
    }
}

// ---------------- LayerNorm over last dim 128 for q and k, in place ----------------
__global__ __launch_bounds__(256) void ln128_kernel(float* __restrict__ qb, float* __restrict__ kb) {
    int wv = threadIdx.x >> 6, ln = threadIdx.x & 63;
    int gw = (blockIdx.x << 2) + wv;      // 0..65535
    float* base = (gw < 32768) ? qb : kb;
    int row = gw & 32767;
    float2 x = *(float2*)(base + (size_t)row * 128 + (ln << 1));
    float s  = x.x + x.y;
    float ss = x.x*x.x + x.y*x.y;
#pragma unroll
    for (int m = 32; m > 0; m >>= 1) { s += __shfl_xor(s, m); ss += __shfl_xor(ss, m); }
    float mu  = s * (1.0f/128.0f);
    float var = ss * (1.0f/128.0f) - mu*mu;
    float r = rsqrtf(var + 1e-6f);
    x.x = (x.x - mu) * r; x.y = (x.y - mu) * r;
    *(float2*)(base + (size_t)row * 128 + (ln << 1)) = x;
}

// ---------------- codebook transpose (H,S,D)->(H,D,S) and squared norms ----------------
__global__ __launch_bounds__(256) void cbt_kernel(const float* __restrict__ cb, float* __restrict__ cT) {
    int idx = blockIdx.x * 256 + threadIdx.x;   // 524288 total
    int h = idx >> 16, s = (idx >> 7) & 511, d = idx & 127;
    cT[((size_t)((h << 7) + d)) * 512 + s] = cb[idx];
}

__global__ __launch_bounds__(256) void cnorm_kernel(const float* __restrict__ cb, float* __restrict__ cn) {
    int wv = threadIdx.x >> 6, ln = threadIdx.x & 63;
    int row = (blockIdx.x << 2) + wv;   // 4096 = H*S
    float2 x = *(const float2*)(cb + (size_t)row * 128 + (ln << 1));
    float ss = x.x*x.x + x.y*x.y;
#pragma unroll
    for (int m = 32; m > 0; m >>= 1) ss += __shfl_xor(ss, m);
    if (ln == 0) cn[row] = ss;
}

// ---------------- VQ: argmin_s (|c|^2 - 2 k.c), overwrite k with codebook[h,z] ----------------
__global__ __launch_bounds__(256) void vq_kernel(float* __restrict__ kb, const float* __restrict__ cT,
                                                 const float* __restrict__ cn, const float* __restrict__ cb) {
    __shared__ float sK[4][4][128];
    int wv = threadIdx.x >> 6, ln = threadIdx.x & 63;
    int gw = (blockIdx.x << 2) + wv;     // 0..8191 waves, 4 rows each
    int bh = gw >> 7;                    // b*8+h
    int l4 = (gw & 127) << 2;
    int h = bh & 7;
    size_t r0 = ((size_t)bh << 9) + l4;
#pragma unroll
    for (int i = 0; i < 4; ++i) {
        float2 kx = *(const float2*)(kb + (r0 + i) * 128 + (ln << 1));
        sK[wv][i][(ln<<1)]   = kx.x;
        sK[wv][i][(ln<<1)+1] = kx.y;
    }
    __syncthreads();
    const float* ct = cT + ((size_t)h << 7) * 512;
    int s0 = ln << 3;
    float dt[4][8];
#pragma unroll
    for (int i = 0; i < 4; ++i)
#pragma unroll
        for (int j = 0; j < 8; ++j) dt[i][j] = 0.0f;

    for (int dc = 0; dc < 4; ++dc) {
        float ch[4][8];
#pragma unroll
        for (int i = 0; i < 4; ++i)
#pragma unroll
            for (int j = 0; j < 8; ++j) ch[i][j] = 0.0f;
#pragma unroll 4
        for (int d = dc * 32; d < dc * 32 + 32; ++d) {
            float4 c0 = ld4(ct + (size_t)d * 512 + s0);
            float4 c1 = ld4(ct + (size_t)d * 512 + s0 + 4);
#pragma unroll
            for (int i = 0; i < 4; ++i) {
                float kd = sK[wv][i][d];
                ch[i][0] += kd * c0.x; ch[i][1] += kd * c0.y; ch[i][2] += kd * c0.z; ch[i][3] += kd * c0.w;
                ch[i][4] += kd * c1.x; ch[i][5] += kd * c1.y; ch[i][6] += kd * c1.z; ch[i][7] += kd * c1.w;
            }
        }
#pragma unroll
        for (int i = 0; i < 4; ++i)
#pragma unroll
            for (int j = 0; j < 8; ++j) dt[i][j] += ch[i][j];
    }
    const float* cnh = cn + (h << 9);
#pragma unroll
    for (int i = 0; i < 4; ++i) {
        float bestv = cnh[s0] - 2.0f * dt[i][0];
        int bestz = s0;
#pragma unroll
        for (int j = 1; j < 8; ++j) {
            float scv = cnh[s0 + j] - 2.0f * dt[i][j];
            if (scv < bestv) { bestv = scv; bestz = s0 + j; }
        }
#pragma unroll
        for (int m = 32; m > 0; m >>= 1) {
            float ov = __shfl_xor(bestv, m);
            int   oz = __shfl_xor(bestz, m);
            if (ov < bestv || (ov == bestv && oz < bestz)) { bestv = ov; bestz = oz; }
        }
        float2 cz = *(const float2*)(cb + ((size_t)(h << 9) + bestz) * 128 + (ln << 1));
        *(float2*)(kb + (r0 + i) * 128 + (ln << 1)) = cz;
    }
}

// ---------------- fused attention: per (b,h,16-query tile) ----------------
__global__ __launch_bounds__(256) void attn_kernel(
        const float* __restrict__ qb,    // (B,H,L,128) LN'd q
        const float* __restrict__ khat,  // (B,H,L,128) quantized k
        const float* __restrict__ vb,    // (B,H,L,128)
        const float* __restrict__ xl_k,  // (B,H,512,128)
        const float* __restrict__ xl_v,  // (B,H,512,128)
        const float* __restrict__ xl_r,  // (H,1024,128)
        const float* __restrict__ cb,    // (H,512,128)
        const float* __restrict__ agg_u, // (B,H,512,128)
        const float* __restrict__ agg_l, // (B,H,512)
        const float* __restrict__ x_u,   // (H,128)
        const float* __restrict__ x_v,   // (H,128)
        const float* __restrict__ gbuf,  // (B,L,1024)
        float* __restrict__ wvg) {       // (B,L,1024) output: wv*g
    __shared__ float Qu[16 * 132];
    __shared__ float Qv[16 * 132];
    __shared__ float Ks[32 * 132];
    __shared__ float RVs[48 * 132];   // union: rel-emb tile (48 rows) then V tile (32 rows)
    __shared__ float Sl[16 * 36];
    __shared__ float biasS[32];

    int t = threadIdx.x;
    int wv = t >> 6, ln = t & 63;
    int blk = blockIdx.x;
    int b = blk >> 8;
    int h = (blk >> 5) & 7;
    int l0 = (blk & 31) << 4;
    int bh = (b << 3) + h;

    const float* qrow = qb + ((size_t)bh * 512 + l0) * 128;
    for (int i = t; i < 512; i += 256) {       // 16 rows x 32 float4
        int r = i >> 5, dq = (i & 31) << 2;
        float4 q4 = ld4(qrow + (size_t)r * 128 + dq);
        float4 u4 = ld4(x_u + (h << 7) + dq);
        float4 v4 = ld4(x_v + (h << 7) + dq);
        float4 a, c;
        a.x = q4.x + u4.x; a.y = q4.y + u4.y; a.z = q4.z + u4.z; a.w = q4.w + u4.w;
        c.x = q4.x + v4.x; c.y = q4.y + v4.y; c.z = q4.z + v4.z; c.w = q4.w + v4.w;
        *(float4*)&Qu[r * 132 + dq] = a;
        *(float4*)&Qv[r * 132 + dq] = c;
    }

    float mrow[4], den[4], o0[4], o1[4];
#pragma unroll
    for (int i = 0; i < 4; ++i) { mrow[i] = -INF30; den[i] = 0.0f; o0[i] = 0.0f; o1[i] = 0.0f; }

    int nt = (l0 + 559) >> 5;   // recent tiles of 32 keys (max 32)
    int ntt = nt + 16;          // + 16 cache tiles (512 codes)

    for (int tile = 0; tile < ntt; ++tile) {
        int recent = (tile < nt);
        int w0 = recent ? (tile << 5) : ((tile - nt) << 5);
        __syncthreads();
        // ---- stage K tile (32 rows x 128) ----
        const float* Kg;
        if (recent) Kg = (w0 < 512) ? (xl_k + ((size_t)bh * 512 + w0) * 128)
                                    : (khat + ((size_t)bh * 512 + (w0 - 512)) * 128);
        else        Kg = cb + ((size_t)(h << 9) + w0) * 128;
        for (int i = t; i < 1024; i += 256) {
            int rr = i >> 5, fq = (i & 31) << 2;
            *(float4*)&Ks[rr * 132 + fq] = ld4(Kg + (size_t)rr * 128 + fq);
        }
        // ---- stage rel-emb tile or cache bias ----
        if (recent) {
            int j0 = w0 + 496 - l0;
            for (int i = t; i < 1536; i += 256) {
                int rr = i >> 5, fq = (i & 31) << 2;
                int j = j0 + rr;
                float4 rv = make_float4(0.f, 0.f, 0.f, 0.f);
                if (rr < 47 && j < 1024) rv = ld4(xl_r + ((size_t)(h << 10) + j) * 128 + fq);
                *(float4*)&RVs[rr * 132 + fq] = rv;
            }
        } else {
            if (t < 32) {
                float al = agg_l[(size_t)bh * 512 + w0 + t];
                biasS[t] = (al > 0.0f) ? __logf(fmaxf(al, 1e-30f)) : -INF30;
            }
        }
        __syncthreads();
        // ---- scores: thread = (row r, 2 keys) ----
        {
            int r = t & 15, kg = t >> 4;
            int k0l = kg << 1;
            const float* qup = Qu + r * 132;
            const float* qvp = Qv + r * 132;
            const float* kp0 = Ks + k0l * 132;
            const float* kp1 = kp0 + 132;
            float a0 = 0.0f, a1 = 0.0f;
            if (recent) {
                int ofs = k0l + 15 - r;
                const float* rp0 = RVs + ofs * 132;
                const float* rp1 = rp0 + 132;
                float b0 = 0.0f, b1 = 0.0f;
#pragma unroll 8
                for (int d = 0; d < 128; d += 4) {
                    float4 u = ld4(qup + d), w = ld4(qvp + d);
                    float4 ka = ld4(kp0 + d), kc = ld4(kp1 + d);
                    float4 ra = ld4(rp0 + d), rc = ld4(rp1 + d);
                    a0 += u.x*ka.x + u.y*ka.y + u.z*ka.z + u.w*ka.w;
                    a1 += u.x*kc.x + u.y*kc.y + u.z*kc.z + u.w*kc.w;
                    b0 += w.x*ra.x + w.y*ra.y + w.z*ra.z + w.w*ra.w;
                    b1 += w.x*rc.x + w.y*rc.y + w.z*rc.z + w.w*rc.w;
                }
                a0 = (a0 + b0) * INV_TAU;
                a1 = (a1 + b1) * INV_TAU;
                int l = l0 + r;
                int wkey = w0 + k0l;
                if (wkey     > l + 512) a0 = -INF30;
                if (wkey + 1 > l + 512) a1 = -INF30;
            } else {
#pragma unroll 8
                for (int d = 0; d < 128; d += 4) {
                    float4 u = ld4(qup + d);
                    float4 ka = ld4(kp0 + d), kc = ld4(kp1 + d);
                    a0 += u.x*ka.x + u.y*ka.y + u.z*ka.z + u.w*ka.w;
                    a1 += u.x*kc.x + u.y*kc.y + u.z*kc.z + u.w*kc.w;
                }
                a0 = a0 * INV_TAU + biasS[k0l];
                a1 = a1 * INV_TAU + biasS[k0l + 1];
            }
            Sl[r * 36 + k0l]     = a0;
            Sl[r * 36 + k0l + 1] = a1;
        }
        __syncthreads();
        // ---- stage V tile over RVs ----
        const float* Vg;
        if (recent) Vg = (w0 < 512) ? (xl_v + ((size_t)bh * 512 + w0) * 128)
                                    : (vb + ((size_t)bh * 512 + (w0 - 512)) * 128);
        else        Vg = agg_u + ((size_t)bh * 512 + w0) * 128;
        for (int i = t; i < 1024; i += 256) {
            int rr = i >> 5, fq = (i & 31) << 2;
            *(float4*)&RVs[rr * 132 + fq] = ld4(Vg + (size_t)rr * 128 + fq);
        }
        __syncthreads();
        // ---- online softmax + O update; wave owns rows 4*wv..4*wv+3, lane owns dims 2*ln,2*ln+1 ----
#pragma unroll
        for (int i = 0; i < 4; ++i) {
            int rr = (wv << 2) + i;
            float sc = Sl[rr * 36 + (ln & 31)];
            float mt = sc;
#pragma unroll
            for (int m = 16; m > 0; m >>= 1) mt = fmaxf(mt, __shfl_xor(mt, m));
            float mnew = fmaxf(mrow[i], mt);
            float a = __expf(sc - mnew);
            float ssum = a;
#pragma unroll
            for (int m = 16; m > 0; m >>= 1) ssum += __shfl_xor(ssum, m);
            float alpha = __expf(mrow[i] - mnew);
            mrow[i] = mnew;
            den[i] = den[i] * alpha + ssum;
            float oa = o0[i] * alpha, ob = o1[i] * alpha;
#pragma unroll 8
            for (int kk = 0; kk < 32; ++kk) {
                float av = __shfl(a, kk);
                float2 vvv = *(const float2*)&RVs[kk * 132 + (ln << 1)];
                oa += av * vvv.x; ob += av * vvv.y;
            }
            o0[i] = oa; o1[i] = ob;
        }
    }
    // ---- epilogue: wv*g ----
#pragma unroll
    for (int i = 0; i < 4; ++i) {
        int rr = (wv << 2) + i;
        int l = l0 + rr;
        float inv = 1.0f / den[i];
        size_t gi = ((size_t)b * 512 + l) * 1024 + (h << 7) + (ln << 1);
        float2 gg = *(const float2*)(gbuf + gi);
        float2 ov;
        ov.x = o0[i] * inv * gg.x;
        ov.y = o1[i] * inv * gg.y;
        *(float2*)(wvg + gi) = ov;
    }
}

extern "C" void kernel_launch(void* const* d_in, const int* in_sizes, int n_in,
                              void* d_out, int out_size, void* d_ws, size_t ws_size,
                              hipStream_t stream) {
    const float* x_in  = (const float*)d_in[0];
    const float* xl_k  = (const float*)d_in[2];
    const float* xl_v  = (const float*)d_in[3];
    const float* agg_u = (const float*)d_in[4];
    const float* agg_l = (const float*)d_in[5];
    const float* W_q   = (const float*)d_in[6];
    const float* W_kvg = (const float*)d_in[7];
    const float* W_res = (const float*)d_in[8];
    const float* x_u   = (const float*)d_in[9];
    const float* x_v   = (const float*)d_in[10];
    const float* xl_r  = (const float*)d_in[11];
    const float* cbk   = (const float*)d_in[12];
    float* out = (float*)d_out;
    float* ws  = (float*)d_ws;

    float* x_t  = ws;                  // 4096*1024
    float* qbuf = x_t  + 4194304;      // (B,H,L,128)
    float* kbuf = qbuf + 4194304;      // k -> khat in place
    float* vbuf = kbuf + 4194304;
    float* gbuf = vbuf + 4194304;      // (B,L,1024) silu gate
    float* wvg  = gbuf + 4194304;      // (B,L,1024) attention out * g
    float* cT   = wvg  + 4194304;      // (H,128,512)
    float* cnm  = cT   + 524288;       // (H,512)

    ln_dm_kernel<<<4096, 256, 0, stream>>>(x_in, x_t);
    gemm_kernel<<<dim3(16, 64), 256, 0, stream>>>(x_t, W_q, 1024, 0, qbuf, nullptr, nullptr);
    gemm_kernel<<<dim3(48, 64), 256, 0, stream>>>(x_t, W_kvg, 3072, 1, kbuf, vbuf, gbuf);
    ln128_kernel<<<16384, 256, 0, stream>>>(qbuf, kbuf);
    cbt_kernel<<<2048, 256, 0, stream>>>(cbk, cT);
    cnorm_kernel<<<1024, 256, 0, stream>>>(cbk, cnm);
    vq_kernel<<<2048, 256, 0, stream>>>(kbuf, cT, cnm, cbk);
    attn_kernel<<<2048, 256, 0, stream>>>(qbuf, kbuf, vbuf, xl_k, xl_v, xl_r, cbk,
                                          agg_u, agg_l, x_u, x_v, gbuf, wvg);
    gemm_kernel<<<dim3(16, 64), 256, 0, stream>>>(wvg, W_res, 1024, 2, out, nullptr, nullptr);
}

// Round 2
// 1534.669 us; speedup vs baseline: 2.0111x; 2.0111x over previous
//
#include <hip/hip_runtime.h>

#define INF30 1e30f
#define INV_TAU 0.08838834764831845f

typedef unsigned short ushort_t;
typedef __attribute__((ext_vector_type(8))) short bf16x8;
typedef __attribute__((ext_vector_type(4))) float f32x4;
typedef __attribute__((ext_vector_type(8))) unsigned short us8;

__device__ __forceinline__ float4 ld4(const float* p) { return *(const float4*)p; }

__device__ __forceinline__ unsigned short bf16_rne(float x) {
    unsigned int u = __float_as_uint(x);
    unsigned int r = u + 0x7fffu + ((u >> 16) & 1u);
    return (unsigned short)(r >> 16);
}
__device__ __forceinline__ float bf16_tof(unsigned short h) {
    return __uint_as_float(((unsigned int)h) << 16);
}
__device__ __forceinline__ bf16x8 ldb8(const ushort_t* p) { return *(const bf16x8*)p; }

#define MFMA16(a, b, c) __builtin_amdgcn_mfma_f32_16x16x32_bf16((a), (b), (c), 0, 0, 0)

// ---------------- LayerNorm over DM=1024 (no affine) ----------------
__global__ __launch_bounds__(256) void ln_dm_kernel(const float* __restrict__ x, float* __restrict__ y) {
    size_t row = blockIdx.x;
    const float4* xr = (const float4*)(x + row * 1024);
    float4 v = xr[threadIdx.x];
    float s  = v.x + v.y + v.z + v.w;
    float ss = v.x*v.x + v.y*v.y + v.z*v.z + v.w*v.w;
#pragma unroll
    for (int off = 32; off > 0; off >>= 1) {
        s  += __shfl_down(s, off);
        ss += __shfl_down(ss, off);
    }
    __shared__ float rs[4], rss[4];
    int wv = threadIdx.x >> 6, ln = threadIdx.x & 63;
    if (ln == 0) { rs[wv] = s; rss[wv] = ss; }
    __syncthreads();
    s  = rs[0] + rs[1] + rs[2] + rs[3];
    ss = rss[0] + rss[1] + rss[2] + rss[3];
    float mu  = s * (1.0f/1024.0f);
    float var = ss * (1.0f/1024.0f) - mu*mu;
    float r = rsqrtf(var + 1e-6f);
    float4 o;
    o.x = (v.x - mu) * r; o.y = (v.y - mu) * r; o.z = (v.z - mu) * r; o.w = (v.w - mu) * r;
    ((float4*)(y + row * 1024))[threadIdx.x] = o;
}

// ---------------- fp32 tiled GEMM (unchanged from R1) ----------------
__global__ __launch_bounds__(256) void gemm_kernel(const float* __restrict__ A, const float* __restrict__ W,
                                                   int N, int mode,
                                                   float* __restrict__ o0, float* __restrict__ o1,
                                                   float* __restrict__ o2) {
    __shared__ float As[16][64];
    __shared__ float Bs[16][64];
    int t = threadIdx.x;
    int col0 = blockIdx.x << 6;
    int row0 = blockIdx.y << 6;
    int tx = t & 15, ty = t >> 4;
    int arow = t >> 2, akq = t & 3;
    int bkr = t >> 4, bcq = t & 15;
    const float* Ap = A + (size_t)(row0 + arow) * 1024 + akq * 4;
    const float* Wp = W + (size_t)bkr * N + col0 + bcq * 4;
    float acc[4][4];
#pragma unroll
    for (int i = 0; i < 4; ++i)
#pragma unroll
        for (int j = 0; j < 4; ++j) acc[i][j] = 0.0f;

    for (int kt = 0; kt < 64; ++kt) {
        float4 a4 = ld4(Ap + kt * 16);
        float4 b4 = ld4(Wp + (size_t)kt * 16 * N);
        __syncthreads();
        As[akq*4+0][arow] = a4.x;
        As[akq*4+1][arow] = a4.y;
        As[akq*4+2][arow] = a4.z;
        As[akq*4+3][arow] = a4.w;
        *(float4*)&Bs[bkr][bcq*4] = b4;
        __syncthreads();
#pragma unroll
        for (int kk = 0; kk < 16; ++kk) {
            float4 av = *(float4*)&As[kk][ty*4];
            float4 bv = *(float4*)&Bs[kk][tx*4];
            acc[0][0] += av.x*bv.x; acc[0][1] += av.x*bv.y; acc[0][2] += av.x*bv.z; acc[0][3] += av.x*bv.w;
            acc[1][0] += av.y*bv.x; acc[1][1] += av.y*bv.y; acc[1][2] += av.y*bv.z; acc[1][3] += av.y*bv.w;
            acc[2][0] += av.z*bv.x; acc[2][1] += av.z*bv.y; acc[2][2] += av.z*bv.z; acc[2][3] += av.z*bv.w;
            acc[3][0] += av.w*bv.x; acc[3][1] += av.w*bv.y; acc[3][2] += av.w*bv.z; acc[3][3] += av.w*bv.w;
        }
    }

#pragma unroll
    for (int i = 0; i < 4; ++i) {
        int rr = row0 + ty*4 + i;
        int b = rr >> 9, l = rr & 511;
#pragma unroll
        for (int j = 0; j < 4; ++j) {
            int cc = col0 + tx*4 + j;
            float vv = acc[i][j];
            if (mode == 0) {
                o0[((size_t)((b<<3) + (cc>>7)) * 512 + l) * 128 + (cc & 127)] = vv;
            } else if (mode == 1) {
                if (cc < 1024) {
                    o0[((size_t)((b<<3) + (cc>>7)) * 512 + l) * 128 + (cc & 127)] = vv;
                } else if (cc < 2048) {
                    int c2 = cc - 1024;
                    o1[((size_t)((b<<3) + (c2>>7)) * 512 + l) * 128 + (c2 & 127)] = vv;
                } else {
                    o2[(size_t)rr * 1024 + (cc - 2048)] = vv / (1.0f + __expf(-vv));
                }
            } else {
                o0[(size_t)rr * 1024 + cc] = vv;
            }
        }
    }
}

// ---------------- LayerNorm over last dim 128 for q and k, in place ----------------
__global__ __launch_bounds__(256) void ln128_kernel(float* __restrict__ qb, float* __restrict__ kb) {
    int wv = threadIdx.x >> 6, ln = threadIdx.x & 63;
    int gw = (blockIdx.x << 2) + wv;
    float* base = (gw < 32768) ? qb : kb;
    int row = gw & 32767;
    float2 x = *(float2*)(base + (size_t)row * 128 + (ln << 1));
    float s  = x.x + x.y;
    float ss = x.x*x.x + x.y*x.y;
#pragma unroll
    for (int m = 32; m > 0; m >>= 1) { s += __shfl_xor(s, m); ss += __shfl_xor(ss, m); }
    float mu  = s * (1.0f/128.0f);
    float var = ss * (1.0f/128.0f) - mu*mu;
    float r = rsqrtf(var + 1e-6f);
    x.x = (x.x - mu) * r; x.y = (x.y - mu) * r;
    *(float2*)(base + (size_t)row * 128 + (ln << 1)) = x;
}

// ---------------- codebook transpose (H,S,D)->(H,D,S) and squared norms ----------------
__global__ __launch_bounds__(256) void cbt_kernel(const float* __restrict__ cb, float* __restrict__ cT) {
    int idx = blockIdx.x * 256 + threadIdx.x;
    int h = idx >> 16, s = (idx >> 7) & 511, d = idx & 127;
    cT[((size_t)((h << 7) + d)) * 512 + s] = cb[idx];
}

__global__ __launch_bounds__(256) void cnorm_kernel(const float* __restrict__ cb, float* __restrict__ cn) {
    int wv = threadIdx.x >> 6, ln = threadIdx.x & 63;
    int row = (blockIdx.x << 2) + wv;
    float2 x = *(const float2*)(cb + (size_t)row * 128 + (ln << 1));
    float ss = x.x*x.x + x.y*x.y;
#pragma unroll
    for (int m = 32; m > 0; m >>= 1) ss += __shfl_xor(ss, m);
    if (ln == 0) cn[row] = ss;
}

// ---------------- VQ: argmin_s (|c|^2 - 2 k.c), overwrite k with codebook[h,z] ----------------
__global__ __launch_bounds__(256) void vq_kernel(float* __restrict__ kb, const float* __restrict__ cT,
                                                 const float* __restrict__ cn, const float* __restrict__ cb) {
    __shared__ float sK[4][4][128];
    int wv = threadIdx.x >> 6, ln = threadIdx.x & 63;
    int gw = (blockIdx.x << 2) + wv;
    int bh = gw >> 7;
    int l4 = (gw & 127) << 2;
    int h = bh & 7;
    size_t r0 = ((size_t)bh << 9) + l4;
#pragma unroll
    for (int i = 0; i < 4; ++i) {
        float2 kx = *(const float2*)(kb + (r0 + i) * 128 + (ln << 1));
        sK[wv][i][(ln<<1)]   = kx.x;
        sK[wv][i][(ln<<1)+1] = kx.y;
    }
    __syncthreads();
    const float* ct = cT + ((size_t)h << 7) * 512;
    int s0 = ln << 3;
    float dt[4][8];
#pragma unroll
    for (int i = 0; i < 4; ++i)
#pragma unroll
        for (int j = 0; j < 8; ++j) dt[i][j] = 0.0f;

    for (int dc = 0; dc < 4; ++dc) {
        float ch[4][8];
#pragma unroll
        for (int i = 0; i < 4; ++i)
#pragma unroll
            for (int j = 0; j < 8; ++j) ch[i][j] = 0.0f;
#pragma unroll 4
        for (int d = dc * 32; d < dc * 32 + 32; ++d) {
            float4 c0 = ld4(ct + (size_t)d * 512 + s0);
            float4 c1 = ld4(ct + (size_t)d * 512 + s0 + 4);
#pragma unroll
            for (int i = 0; i < 4; ++i) {
                float kd = sK[wv][i][d];
                ch[i][0] += kd * c0.x; ch[i][1] += kd * c0.y; ch[i][2] += kd * c0.z; ch[i][3] += kd * c0.w;
                ch[i][4] += kd * c1.x; ch[i][5] += kd * c1.y; ch[i][6] += kd * c1.z; ch[i][7] += kd * c1.w;
            }
        }
#pragma unroll
        for (int i = 0; i < 4; ++i)
#pragma unroll
            for (int j = 0; j < 8; ++j) dt[i][j] += ch[i][j];
    }
    const float* cnh = cn + (h << 9);
#pragma unroll
    for (int i = 0; i < 4; ++i) {
        float bestv = cnh[s0] - 2.0f * dt[i][0];
        int bestz = s0;
#pragma unroll
        for (int j = 1; j < 8; ++j) {
            float scv = cnh[s0 + j] - 2.0f * dt[i][j];
            if (scv < bestv) { bestv = scv; bestz = s0 + j; }
        }
#pragma unroll
        for (int m = 32; m > 0; m >>= 1) {
            float ov = __shfl_xor(bestv, m);
            int   oz = __shfl_xor(bestz, m);
            if (ov < bestv || (ov == bestv && oz < bestz)) { bestv = ov; bestz = oz; }
        }
        float2 cz = *(const float2*)(cb + ((size_t)(h << 9) + bestz) * 128 + (ln << 1));
        *(float2*)(kb + (r0 + i) * 128 + (ln << 1)) = cz;
    }
}

// ---------------- prep: split q into Qu/Qv (hi/lo bf16) ----------------
__global__ __launch_bounds__(256) void split_q_kernel(const float* __restrict__ q,
        const float* __restrict__ xu, const float* __restrict__ xv,
        ushort_t* __restrict__ quh, ushort_t* __restrict__ qul,
        ushort_t* __restrict__ qvh, ushort_t* __restrict__ qvl) {
    int idx = blockIdx.x * 256 + threadIdx.x;           // 4194304 total
    int d = idx & 127;
    int h = (idx >> 16) & 7;
    float qv = q[idx];
    float a = qv + xu[(h << 7) + d];
    unsigned short ah = bf16_rne(a);
    quh[idx] = ah; qul[idx] = bf16_rne(a - bf16_tof(ah));
    float b = qv + xv[(h << 7) + d];
    unsigned short bh = bf16_rne(b);
    qvh[idx] = bh; qvl[idx] = bf16_rne(b - bf16_tof(bh));
}

// ---------------- prep: generic contiguous split ----------------
__global__ __launch_bounds__(256) void split_plain_kernel(const float* __restrict__ src,
        ushort_t* __restrict__ hi, ushort_t* __restrict__ lo) {
    int idx = blockIdx.x * 256 + threadIdx.x;
    float x = src[idx];
    unsigned short h = bf16_rne(x);
    hi[idx] = h; lo[idx] = bf16_rne(x - bf16_tof(h));
}

// ---------------- prep: split (BH,512,128) into (BH,1024,128) at row offset ----------------
__global__ __launch_bounds__(256) void split_koff_kernel(const float* __restrict__ src,
        ushort_t* __restrict__ hi, ushort_t* __restrict__ lo, int rowoff) {
    int idx = blockIdx.x * 256 + threadIdx.x;           // 4194304 total
    int bh = idx >> 16, rem = idx & 65535;
    size_t dst = ((size_t)bh << 17) + ((size_t)rowoff << 7) + rem;
    float x = src[idx];
    unsigned short h = bf16_rne(x);
    hi[dst] = h; lo[dst] = bf16_rne(x - bf16_tof(h));
}

// ---------------- prep: transpose V (bh, key, 128) -> Vt (bh, 128, NK) + split ----------------
__global__ __launch_bounds__(256) void vtsplit_kernel(const float* __restrict__ srcA,
        const float* __restrict__ srcB, ushort_t* __restrict__ hi, ushort_t* __restrict__ lo, int NK) {
    __shared__ float T[64][132];
    int bh = blockIdx.x, kt = blockIdx.y, t = threadIdx.x;
    for (int i = t; i < 2048; i += 256) {
        int r = i >> 5, c4 = (i & 31) << 2;
        int key = (kt << 6) + r;
        const float* s = (key < 512) ? (srcA + ((size_t)bh * 512 + key) * 128 + c4)
                                     : (srcB + ((size_t)bh * 512 + (key - 512)) * 128 + c4);
        *(float4*)&T[r][c4] = ld4(s);
    }
    __syncthreads();
    for (int i = t; i < 1024; i += 256) {
        int vc = i >> 3, kk = (i & 7) << 3;
        us8 h8, l8;
#pragma unroll
        for (int j = 0; j < 8; ++j) {
            float x = T[kk + j][vc];
            unsigned short hh = bf16_rne(x);
            h8[j] = hh; l8[j] = bf16_rne(x - bf16_tof(hh));
        }
        size_t off = ((size_t)bh * 128 + vc) * NK + (kt << 6) + kk;
        *(us8*)(hi + off) = h8;
        *(us8*)(lo + off) = l8;
    }
}

// ---------------- prep: cache bias ----------------
__global__ __launch_bounds__(256) void cbias_kernel(const float* __restrict__ al, float* __restrict__ cb) {
    int idx = blockIdx.x * 256 + threadIdx.x;           // 32768
    float v = al[idx];
    cb[idx] = (v > 0.0f) ? __logf(fmaxf(v, 1e-30f)) : -INF30;
}

// ---------------- fused MFMA attention ----------------
// block = (bh, 32 q-rows). 4 waves; wave handles 16 keys/iter, 64 keys/iter per block.
__global__ __launch_bounds__(256) void attn2_kernel(
        const ushort_t* __restrict__ Qu_hi, const ushort_t* __restrict__ Qu_lo,   // (64,512,128)
        const ushort_t* __restrict__ Qv_hi, const ushort_t* __restrict__ Qv_lo,   // (64,512,128)
        const ushort_t* __restrict__ K_hi,  const ushort_t* __restrict__ K_lo,    // (64,1024,128)
        const ushort_t* __restrict__ C_hi,  const ushort_t* __restrict__ C_lo,    // (8,512,128)
        const ushort_t* __restrict__ Vt_hi, const ushort_t* __restrict__ Vt_lo,   // (64,128,1024)
        const ushort_t* __restrict__ At_hi, const ushort_t* __restrict__ At_lo,   // (64,128,512)
        const ushort_t* __restrict__ R_hi,  const ushort_t* __restrict__ R_lo,    // (8,1024,128)
        const float* __restrict__ cbias,                                          // (64,512)
        const float* __restrict__ gbuf, float* __restrict__ wvg) {
    __shared__ float G[32 * 116];
    __shared__ __align__(16) ushort_t Ph[32 * 72];
    __shared__ __align__(16) ushort_t Pl[32 * 72];
    __shared__ float cb_s[512];
    __shared__ float pmax[4][32], psum[4][32];
    __shared__ float mrun[32], lrun[32];

    int t = threadIdx.x;
    int wvid = t >> 6, ln = t & 63;
    int col = ln & 15, quad = ln >> 4;
    int blk = blockIdx.x;
    int bh = blk >> 4;
    int l0 = (blk & 15) << 5;
    int h = bh & 7;

    for (int i = t; i < 512; i += 256) cb_s[i] = cbias[(bh << 9) + i];
    if (t < 32) { mrun[t] = -INF30; lrun[t] = 0.0f; }

    // persistent Qu A-frags
    bf16x8 quh[2][4], qul[2][4];
#pragma unroll
    for (int tq = 0; tq < 2; ++tq) {
        const ushort_t* bh_p = Qu_hi + ((size_t)bh * 512 + l0 + 16 * tq + col) * 128 + quad * 8;
        const ushort_t* bl_p = Qu_lo + ((size_t)bh * 512 + l0 + 16 * tq + col) * 128 + quad * 8;
#pragma unroll
        for (int s = 0; s < 4; ++s) {
            quh[tq][s] = ldb8(bh_p + 32 * s);
            qul[tq][s] = ldb8(bl_p + 32 * s);
        }
    }
    __syncthreads();

    f32x4 O[2][2];
#pragma unroll
    for (int a = 0; a < 2; ++a)
#pragma unroll
        for (int b2 = 0; b2 < 2; ++b2) O[a][b2] = (f32x4){0.f, 0.f, 0.f, 0.f};
    float alpha_r[2][4];

    int nrt = (l0 + 607) >> 6;      // ceil((l0+544)/64)
    int total = nrt + 8;

    for (int iter = 0; iter < total; ++iter) {
        bool recent = iter < nrt;
        int w0 = recent ? (iter << 6) : ((iter - nrt) << 6);

        if (recent) {
            // --- cooperative G tiles: rel scores qv . r[j], j = jbase + [0,112) ---
            int jbase = w0 + 480 - l0;
            for (int g = wvid; g < 14; g += 4) {
                int tq = g & 1, jt = g >> 1;
                int jrow = jbase + jt * 16 + col;
                if (jrow > 1023) jrow = 1023;
                const ushort_t* rbh = R_hi + ((size_t)h * 1024 + jrow) * 128 + quad * 8;
                const ushort_t* rbl = R_lo + ((size_t)h * 1024 + jrow) * 128 + quad * 8;
                const ushort_t* qvh_p = Qv_hi + ((size_t)bh * 512 + l0 + 16 * tq + col) * 128 + quad * 8;
                const ushort_t* qvl_p = Qv_lo + ((size_t)bh * 512 + l0 + 16 * tq + col) * 128 + quad * 8;
                f32x4 acc = (f32x4){0.f, 0.f, 0.f, 0.f};
#pragma unroll
                for (int s = 0; s < 4; ++s) {
                    bf16x8 ah = ldb8(qvh_p + 32 * s);
                    bf16x8 al = ldb8(qvl_p + 32 * s);
                    bf16x8 bb = ldb8(rbh + 32 * s);
                    bf16x8 bl = ldb8(rbl + 32 * s);
                    acc = MFMA16(ah, bb, acc);
                    acc = MFMA16(al, bb, acc);
                    acc = MFMA16(ah, bl, acc);
                }
#pragma unroll
                for (int r = 0; r < 4; ++r)
                    G[(16 * tq + 4 * quad + r) * 116 + jt * 16 + col] = acc[r] * INV_TAU;
            }
            __syncthreads();
        }

        // --- phase A: scores for this wave's 16 keys ---
        int kw = w0 + 16 * wvid;
        const ushort_t *kbh_p, *kbl_p;
        if (recent) {
            kbh_p = K_hi + ((size_t)bh * 1024 + kw + col) * 128 + quad * 8;
            kbl_p = K_lo + ((size_t)bh * 1024 + kw + col) * 128 + quad * 8;
        } else {
            kbh_p = C_hi + ((size_t)h * 512 + kw + col) * 128 + quad * 8;
            kbl_p = C_lo + ((size_t)h * 512 + kw + col) * 128 + quad * 8;
        }
        bf16x8 bhf[4], blf[4];
#pragma unroll
        for (int s = 0; s < 4; ++s) {
            bhf[s] = ldb8(kbh_p + 32 * s);
            blf[s] = ldb8(kbl_p + 32 * s);
        }
        f32x4 S[2];
#pragma unroll
        for (int tq = 0; tq < 2; ++tq) {
            f32x4 acc = (f32x4){0.f, 0.f, 0.f, 0.f};
#pragma unroll
            for (int s = 0; s < 4; ++s) {
                acc = MFMA16(quh[tq][s], bhf[s], acc);
                acc = MFMA16(qul[tq][s], bhf[s], acc);
                acc = MFMA16(quh[tq][s], blf[s], acc);
            }
#pragma unroll
            for (int r = 0; r < 4; ++r) {
                int row = 16 * tq + 4 * quad + r;
                float sv = acc[r] * INV_TAU;
                if (recent) {
                    int kloc = 16 * wvid + col;
                    sv += G[row * 116 + kloc + 31 - row];
                    if (w0 + kloc > l0 + row + 512) sv = -INF30;
                } else {
                    sv += cb_s[kw + col];
                }
                acc[r] = sv;
            }
            S[tq] = acc;
        }

        // --- phase B1: per-row tile max ---
#pragma unroll
        for (int tq = 0; tq < 2; ++tq)
#pragma unroll
            for (int r = 0; r < 4; ++r) {
                float mv = S[tq][r];
#pragma unroll
                for (int m = 8; m > 0; m >>= 1) mv = fmaxf(mv, __shfl_xor(mv, m));
                if (col == 0) pmax[wvid][16 * tq + 4 * quad + r] = mv;
            }
        __syncthreads();

        // --- phase B2: softmax, write P ---
#pragma unroll
        for (int tq = 0; tq < 2; ++tq)
#pragma unroll
            for (int r = 0; r < 4; ++r) {
                int row = 16 * tq + 4 * quad + r;
                float mt = fmaxf(fmaxf(pmax[0][row], pmax[1][row]), fmaxf(pmax[2][row], pmax[3][row]));
                float mold = mrun[row];
                float mnew = fmaxf(mold, mt);
                alpha_r[tq][r] = __expf(mold - mnew);
                float p = __expf(S[tq][r] - mnew);
                float ps = p;
#pragma unroll
                for (int m = 8; m > 0; m >>= 1) ps += __shfl_xor(ps, m);
                if (col == 0) psum[wvid][row] = ps;
                unsigned short phh = bf16_rne(p);
                Ph[row * 72 + 16 * wvid + col] = phh;
                Pl[row * 72 + 16 * wvid + col] = bf16_rne(p - bf16_tof(phh));
            }
        __syncthreads();

        // --- update running stats (wave 0) ---
        if (t < 32) {
            float mt = fmaxf(fmaxf(pmax[0][t], pmax[1][t]), fmaxf(pmax[2][t], pmax[3][t]));
            float mold = mrun[t];
            float mnew = fmaxf(mold, mt);
            float al = __expf(mold - mnew);
            lrun[t] = lrun[t] * al + psum[0][t] + psum[1][t] + psum[2][t] + psum[3][t];
            mrun[t] = mnew;
        }

        // --- phase C: PV ---
        bf16x8 pah[2][2], pal[2][2];
#pragma unroll
        for (int tq = 0; tq < 2; ++tq)
#pragma unroll
            for (int s2 = 0; s2 < 2; ++s2) {
                pah[tq][s2] = *(const bf16x8*)&Ph[(16 * tq + col) * 72 + 32 * s2 + quad * 8];
                pal[tq][s2] = *(const bf16x8*)&Pl[(16 * tq + col) * 72 + 32 * s2 + quad * 8];
            }
#pragma unroll
        for (int tq = 0; tq < 2; ++tq)
#pragma unroll
            for (int u = 0; u < 2; ++u)
#pragma unroll
                for (int r = 0; r < 4; ++r) O[tq][u][r] *= alpha_r[tq][r];

        const ushort_t* vth = recent ? (Vt_hi + (size_t)bh * 128 * 1024) : (At_hi + (size_t)bh * 128 * 512);
        const ushort_t* vtl = recent ? (Vt_lo + (size_t)bh * 128 * 1024) : (At_lo + (size_t)bh * 128 * 512);
        size_t vstride = recent ? 1024 : 512;
#pragma unroll
        for (int u = 0; u < 2; ++u) {
            int vcol = 32 * wvid + 16 * u + col;
#pragma unroll
            for (int s2 = 0; s2 < 2; ++s2) {
                bf16x8 vbh = ldb8(vth + (size_t)vcol * vstride + w0 + 32 * s2 + quad * 8);
                bf16x8 vbl = ldb8(vtl + (size_t)vcol * vstride + w0 + 32 * s2 + quad * 8);
#pragma unroll
                for (int tq = 0; tq < 2; ++tq) {
                    O[tq][u] = MFMA16(pah[tq][s2], vbh, O[tq][u]);
                    O[tq][u] = MFMA16(pal[tq][s2], vbh, O[tq][u]);
                    O[tq][u] = MFMA16(pah[tq][s2], vbl, O[tq][u]);
                }
            }
        }
    }
    __syncthreads();

    // --- epilogue: O/lrun * g -> wvg ---
    int b = bh >> 3;
#pragma unroll
    for (int tq = 0; tq < 2; ++tq)
#pragma unroll
        for (int u = 0; u < 2; ++u) {
            int vcol = 32 * wvid + 16 * u + col;
#pragma unroll
            for (int r = 0; r < 4; ++r) {
                int row = 16 * tq + 4 * quad + r;
                float inv = 1.0f / lrun[row];
                size_t gi = ((size_t)b * 512 + l0 + row) * 1024 + (h << 7) + vcol;
                wvg[gi] = O[tq][u][r] * inv * gbuf[gi];
            }
        }
}

extern "C" void kernel_launch(void* const* d_in, const int* in_sizes, int n_in,
                              void* d_out, int out_size, void* d_ws, size_t ws_size,
                              hipStream_t stream) {
    const float* x_in  = (const float*)d_in[0];
    const float* xl_k  = (const float*)d_in[2];
    const float* xl_v  = (const float*)d_in[3];
    const float* agg_u = (const float*)d_in[4];
    const float* agg_l = (const float*)d_in[5];
    const float* W_q   = (const float*)d_in[6];
    const float* W_kvg = (const float*)d_in[7];
    const float* W_res = (const float*)d_in[8];
    const float* x_u   = (const float*)d_in[9];
    const float* x_v   = (const float*)d_in[10];
    const float* xl_r  = (const float*)d_in[11];
    const float* cbk   = (const float*)d_in[12];
    float* out = (float*)d_out;
    char* wb = (char*)d_ws;

    float*  x_t   = (float*)(wb);                       // 16 MB  [alias: K_hi]
    float*  qbuf  = (float*)(wb + 16777216ul);          // 16 MB  [alias: Vt_lo]
    float*  kbuf  = (float*)(wb + 33554432ul);          // 16 MB  [alias: Vt_hi]
    float*  vbuf  = (float*)(wb + 50331648ul);          // 16 MB  [alias: At_hi+At_lo]
    float*  gbuf  = (float*)(wb + 67108864ul);          // 16 MB
    float*  wvg   = (float*)(wb + 83886080ul);          // 16 MB
    float*  cT    = (float*)(wb + 100663296ul);         // 2 MB   [alias: C_hi+C_lo]
    float*  cnm   = (float*)(wb + 102760448ul);         // 16 KB
    ushort_t* Qu_hi = (ushort_t*)(wb + 102776832ul);    // 8 MB
    ushort_t* Qu_lo = (ushort_t*)(wb + 111165440ul);
    ushort_t* Qv_hi = (ushort_t*)(wb + 119554048ul);
    ushort_t* Qv_lo = (ushort_t*)(wb + 127942656ul);
    ushort_t* K_lo  = (ushort_t*)(wb + 136331264ul);    // 16 MB
    ushort_t* R_hi  = (ushort_t*)(wb + 153108480ul);    // 2 MB
    ushort_t* R_lo  = (ushort_t*)(wb + 155205632ul);    // 2 MB
    float*  cbias   = (float*)(wb + 157302784ul);       // 128 KB

    ushort_t* K_hi  = (ushort_t*)x_t;
    ushort_t* Vt_hi = (ushort_t*)kbuf;
    ushort_t* Vt_lo = (ushort_t*)qbuf;
    ushort_t* At_hi = (ushort_t*)vbuf;
    ushort_t* At_lo = (ushort_t*)(wb + 50331648ul + 8388608ul);
    ushort_t* C_hi  = (ushort_t*)cT;
    ushort_t* C_lo  = (ushort_t*)(wb + 100663296ul + 1048576ul);

    ln_dm_kernel<<<4096, 256, 0, stream>>>(x_in, x_t);
    gemm_kernel<<<dim3(16, 64), 256, 0, stream>>>(x_t, W_q, 1024, 0, qbuf, nullptr, nullptr);
    gemm_kernel<<<dim3(48, 64), 256, 0, stream>>>(x_t, W_kvg, 3072, 1, kbuf, vbuf, gbuf);
    ln128_kernel<<<16384, 256, 0, stream>>>(qbuf, kbuf);
    cbt_kernel<<<2048, 256, 0, stream>>>(cbk, cT);
    cnorm_kernel<<<1024, 256, 0, stream>>>(cbk, cnm);
    vq_kernel<<<2048, 256, 0, stream>>>(kbuf, cT, cnm, cbk);
    // prep splits
    split_q_kernel<<<16384, 256, 0, stream>>>(qbuf, x_u, x_v, Qu_hi, Qu_lo, Qv_hi, Qv_lo);
    split_koff_kernel<<<16384, 256, 0, stream>>>(xl_k, K_hi, K_lo, 0);
    split_koff_kernel<<<16384, 256, 0, stream>>>(kbuf, K_hi, K_lo, 512);
    split_plain_kernel<<<2048, 256, 0, stream>>>(cbk, C_hi, C_lo);
    split_plain_kernel<<<4096, 256, 0, stream>>>(xl_r, R_hi, R_lo);
    vtsplit_kernel<<<dim3(64, 16), 256, 0, stream>>>(xl_v, vbuf, Vt_hi, Vt_lo, 1024);
    vtsplit_kernel<<<dim3(64, 8), 256, 0, stream>>>(agg_u, agg_u, At_hi, At_lo, 512);
    cbias_kernel<<<128, 256, 0, stream>>>(agg_l, cbias);
    // fused attention
    attn2_kernel<<<1024, 256, 0, stream>>>(Qu_hi, Qu_lo, Qv_hi, Qv_lo, K_hi, K_lo, C_hi, C_lo,
                                           Vt_hi, Vt_lo, At_hi, At_lo, R_hi, R_lo,
                                           cbias, gbuf, wvg);
    gemm_kernel<<<dim3(16, 64), 256, 0, stream>>>(wvg, W_res, 1024, 2, out, nullptr, nullptr);
}

// Round 3
// 1306.918 us; speedup vs baseline: 2.3616x; 1.1743x over previous
//
#include <hip/hip_runtime.h>

#define INF30 1e30f
#define INV_TAU 0.08838834764831845f

typedef unsigned short ushort_t;
typedef __attribute__((ext_vector_type(8))) short bf16x8;
typedef __attribute__((ext_vector_type(4))) float f32x4;
typedef __attribute__((ext_vector_type(8))) unsigned short us8;

__device__ __forceinline__ float4 ld4(const float* p) { return *(const float4*)p; }

__device__ __forceinline__ unsigned short bf16_rne(float x) {
    unsigned int u = __float_as_uint(x);
    unsigned int r = u + 0x7fffu + ((u >> 16) & 1u);
    return (unsigned short)(r >> 16);
}
__device__ __forceinline__ float bf16_tof(unsigned short h) {
    return __uint_as_float(((unsigned int)h) << 16);
}
__device__ __forceinline__ bf16x8 ldb8(const ushort_t* p) { return *(const bf16x8*)p; }

#define MFMA16(a, b, c) __builtin_amdgcn_mfma_f32_16x16x32_bf16((a), (b), (c), 0, 0, 0)

// ---------------- LayerNorm over DM=1024 (no affine) ----------------
__global__ __launch_bounds__(256) void ln_dm_kernel(const float* __restrict__ x, float* __restrict__ y) {
    size_t row = blockIdx.x;
    const float4* xr = (const float4*)(x + row * 1024);
    float4 v = xr[threadIdx.x];
    float s  = v.x + v.y + v.z + v.w;
    float ss = v.x*v.x + v.y*v.y + v.z*v.z + v.w*v.w;
#pragma unroll
    for (int off = 32; off > 0; off >>= 1) {
        s  += __shfl_down(s, off);
        ss += __shfl_down(ss, off);
    }
    __shared__ float rs[4], rss[4];
    int wv = threadIdx.x >> 6, ln = threadIdx.x & 63;
    if (ln == 0) { rs[wv] = s; rss[wv] = ss; }
    __syncthreads();
    s  = rs[0] + rs[1] + rs[2] + rs[3];
    ss = rss[0] + rss[1] + rss[2] + rss[3];
    float mu  = s * (1.0f/1024.0f);
    float var = ss * (1.0f/1024.0f) - mu*mu;
    float r = rsqrtf(var + 1e-6f);
    float4 o;
    o.x = (v.x - mu) * r; o.y = (v.y - mu) * r; o.z = (v.z - mu) * r; o.w = (v.w - mu) * r;
    ((float4*)(y + row * 1024))[threadIdx.x] = o;
}

// ---------------- fp32 tiled GEMM ----------------
__global__ __launch_bounds__(256) void gemm_kernel(const float* __restrict__ A, const float* __restrict__ W,
                                                   int N, int mode,
                                                   float* __restrict__ o0, float* __restrict__ o1,
                                                   float* __restrict__ o2) {
    __shared__ float As[16][64];
    __shared__ float Bs[16][64];
    int t = threadIdx.x;
    int col0 = blockIdx.x << 6;
    int row0 = blockIdx.y << 6;
    int tx = t & 15, ty = t >> 4;
    int arow = t >> 2, akq = t & 3;
    int bkr = t >> 4, bcq = t & 15;
    const float* Ap = A + (size_t)(row0 + arow) * 1024 + akq * 4;
    const float* Wp = W + (size_t)bkr * N + col0 + bcq * 4;
    float acc[4][4];
#pragma unroll
    for (int i = 0; i < 4; ++i)
#pragma unroll
        for (int j = 0; j < 4; ++j) acc[i][j] = 0.0f;

    for (int kt = 0; kt < 64; ++kt) {
        float4 a4 = ld4(Ap + kt * 16);
        float4 b4 = ld4(Wp + (size_t)kt * 16 * N);
        __syncthreads();
        As[akq*4+0][arow] = a4.x;
        As[akq*4+1][arow] = a4.y;
        As[akq*4+2][arow] = a4.z;
        As[akq*4+3][arow] = a4.w;
        *(float4*)&Bs[bkr][bcq*4] = b4;
        __syncthreads();
#pragma unroll
        for (int kk = 0; kk < 16; ++kk) {
            float4 av = *(float4*)&As[kk][ty*4];
            float4 bv = *(float4*)&Bs[kk][tx*4];
            acc[0][0] += av.x*bv.x; acc[0][1] += av.x*bv.y; acc[0][2] += av.x*bv.z; acc[0][3] += av.x*bv.w;
            acc[1][0] += av.y*bv.x; acc[1][1] += av.y*bv.y; acc[1][2] += av.y*bv.z; acc[1][3] += av.y*bv.w;
            acc[2][0] += av.z*bv.x; acc[2][1] += av.z*bv.y; acc[2][2] += av.z*bv.z; acc[2][3] += av.z*bv.w;
            acc[3][0] += av.w*bv.x; acc[3][1] += av.w*bv.y; acc[3][2] += av.w*bv.z; acc[3][3] += av.w*bv.w;
        }
    }

#pragma unroll
    for (int i = 0; i < 4; ++i) {
        int rr = row0 + ty*4 + i;
        int b = rr >> 9, l = rr & 511;
#pragma unroll
        for (int j = 0; j < 4; ++j) {
            int cc = col0 + tx*4 + j;
            float vv = acc[i][j];
            if (mode == 0) {
                o0[((size_t)((b<<3) + (cc>>7)) * 512 + l) * 128 + (cc & 127)] = vv;
            } else if (mode == 1) {
                if (cc < 1024) {
                    o0[((size_t)((b<<3) + (cc>>7)) * 512 + l) * 128 + (cc & 127)] = vv;
                } else if (cc < 2048) {
                    int c2 = cc - 1024;
                    o1[((size_t)((b<<3) + (c2>>7)) * 512 + l) * 128 + (c2 & 127)] = vv;
                } else {
                    o2[(size_t)rr * 1024 + (cc - 2048)] = vv / (1.0f + __expf(-vv));
                }
            } else {
                o0[(size_t)rr * 1024 + cc] = vv;
            }
        }
    }
}

// ---------------- LayerNorm over last dim 128 for q and k, in place ----------------
__global__ __launch_bounds__(256) void ln128_kernel(float* __restrict__ qb, float* __restrict__ kb) {
    int wv = threadIdx.x >> 6, ln = threadIdx.x & 63;
    int gw = (blockIdx.x << 2) + wv;
    float* base = (gw < 32768) ? qb : kb;
    int row = gw & 32767;
    float2 x = *(float2*)(base + (size_t)row * 128 + (ln << 1));
    float s  = x.x + x.y;
    float ss = x.x*x.x + x.y*x.y;
#pragma unroll
    for (int m = 32; m > 0; m >>= 1) { s += __shfl_xor(s, m); ss += __shfl_xor(ss, m); }
    float mu  = s * (1.0f/128.0f);
    float var = ss * (1.0f/128.0f) - mu*mu;
    float r = rsqrtf(var + 1e-6f);
    x.x = (x.x - mu) * r; x.y = (x.y - mu) * r;
    *(float2*)(base + (size_t)row * 128 + (ln << 1)) = x;
}

// ---------------- codebook transpose (H,S,D)->(H,D,S) and squared norms ----------------
__global__ __launch_bounds__(256) void cbt_kernel(const float* __restrict__ cb, float* __restrict__ cT) {
    int idx = blockIdx.x * 256 + threadIdx.x;
    int h = idx >> 16, s = (idx >> 7) & 511, d = idx & 127;
    cT[((size_t)((h << 7) + d)) * 512 + s] = cb[idx];
}

__global__ __launch_bounds__(256) void cnorm_kernel(const float* __restrict__ cb, float* __restrict__ cn) {
    int wv = threadIdx.x >> 6, ln = threadIdx.x & 63;
    int row = (blockIdx.x << 2) + wv;
    float2 x = *(const float2*)(cb + (size_t)row * 128 + (ln << 1));
    float ss = x.x*x.x + x.y*x.y;
#pragma unroll
    for (int m = 32; m > 0; m >>= 1) ss += __shfl_xor(ss, m);
    if (ln == 0) cn[row] = ss;
}

// ---------------- VQ: argmin_s (|c|^2 - 2 k.c), overwrite k with codebook[h,z] ----------------
__global__ __launch_bounds__(256) void vq_kernel(float* __restrict__ kb, const float* __restrict__ cT,
                                                 const float* __restrict__ cn, const float* __restrict__ cb) {
    __shared__ float sK[4][4][128];
    int wv = threadIdx.x >> 6, ln = threadIdx.x & 63;
    int gw = (blockIdx.x << 2) + wv;
    int bh = gw >> 7;
    int l4 = (gw & 127) << 2;
    int h = bh & 7;
    size_t r0 = ((size_t)bh << 9) + l4;
#pragma unroll
    for (int i = 0; i < 4; ++i) {
        float2 kx = *(const float2*)(kb + (r0 + i) * 128 + (ln << 1));
        sK[wv][i][(ln<<1)]   = kx.x;
        sK[wv][i][(ln<<1)+1] = kx.y;
    }
    __syncthreads();
    const float* ct = cT + ((size_t)h << 7) * 512;
    int s0 = ln << 3;
    float dt[4][8];
#pragma unroll
    for (int i = 0; i < 4; ++i)
#pragma unroll
        for (int j = 0; j < 8; ++j) dt[i][j] = 0.0f;

    for (int dc = 0; dc < 4; ++dc) {
        float ch[4][8];
#pragma unroll
        for (int i = 0; i < 4; ++i)
#pragma unroll
            for (int j = 0; j < 8; ++j) ch[i][j] = 0.0f;
#pragma unroll 4
        for (int d = dc * 32; d < dc * 32 + 32; ++d) {
            float4 c0 = ld4(ct + (size_t)d * 512 + s0);
            float4 c1 = ld4(ct + (size_t)d * 512 + s0 + 4);
#pragma unroll
            for (int i = 0; i < 4; ++i) {
                float kd = sK[wv][i][d];
                ch[i][0] += kd * c0.x; ch[i][1] += kd * c0.y; ch[i][2] += kd * c0.z; ch[i][3] += kd * c0.w;
                ch[i][4] += kd * c1.x; ch[i][5] += kd * c1.y; ch[i][6] += kd * c1.z; ch[i][7] += kd * c1.w;
            }
        }
#pragma unroll
        for (int i = 0; i < 4; ++i)
#pragma unroll
            for (int j = 0; j < 8; ++j) dt[i][j] += ch[i][j];
    }
    const float* cnh = cn + (h << 9);
#pragma unroll
    for (int i = 0; i < 4; ++i) {
        float bestv = cnh[s0] - 2.0f * dt[i][0];
        int bestz = s0;
#pragma unroll
        for (int j = 1; j < 8; ++j) {
            float scv = cnh[s0 + j] - 2.0f * dt[i][j];
            if (scv < bestv) { bestv = scv; bestz = s0 + j; }
        }
#pragma unroll
        for (int m = 32; m > 0; m >>= 1) {
            float ov = __shfl_xor(bestv, m);
            int   oz = __shfl_xor(bestz, m);
            if (ov < bestv || (ov == bestv && oz < bestz)) { bestv = ov; bestz = oz; }
        }
        float2 cz = *(const float2*)(cb + ((size_t)(h << 9) + bestz) * 128 + (ln << 1));
        *(float2*)(kb + (r0 + i) * 128 + (ln << 1)) = cz;
    }
}

// ---------------- prep: split q into Qu (hi/lo) / Qv (hi) ----------------
__global__ __launch_bounds__(256) void split_q_kernel(const float* __restrict__ q,
        const float* __restrict__ xu, const float* __restrict__ xv,
        ushort_t* __restrict__ quh, ushort_t* __restrict__ qul,
        ushort_t* __restrict__ qvh) {
    int idx = blockIdx.x * 256 + threadIdx.x;           // 4194304 total
    int d = idx & 127;
    int h = (idx >> 16) & 7;
    float qv = q[idx];
    float a = qv + xu[(h << 7) + d];
    unsigned short ah = bf16_rne(a);
    quh[idx] = ah; qul[idx] = bf16_rne(a - bf16_tof(ah));
    float b = qv + xv[(h << 7) + d];
    qvh[idx] = bf16_rne(b);
}

// ---------------- prep: generic contiguous split ----------------
__global__ __launch_bounds__(256) void split_plain_kernel(const float* __restrict__ src,
        ushort_t* __restrict__ hi, ushort_t* __restrict__ lo) {
    int idx = blockIdx.x * 256 + threadIdx.x;
    float x = src[idx];
    unsigned short h = bf16_rne(x);
    hi[idx] = h; lo[idx] = bf16_rne(x - bf16_tof(h));
}

// ---------------- prep: hi-only bf16 convert ----------------
__global__ __launch_bounds__(256) void cvt_hi_kernel(const float* __restrict__ src,
        ushort_t* __restrict__ hi) {
    int idx = blockIdx.x * 256 + threadIdx.x;
    hi[idx] = bf16_rne(src[idx]);
}

// ---------------- prep: split (BH,512,128) into (BH,1024,128) at row offset ----------------
__global__ __launch_bounds__(256) void split_koff_kernel(const float* __restrict__ src,
        ushort_t* __restrict__ hi, ushort_t* __restrict__ lo, int rowoff) {
    int idx = blockIdx.x * 256 + threadIdx.x;           // 4194304 total
    int bh = idx >> 16, rem = idx & 65535;
    size_t dst = ((size_t)bh << 17) + ((size_t)rowoff << 7) + rem;
    float x = src[idx];
    unsigned short h = bf16_rne(x);
    hi[dst] = h; lo[dst] = bf16_rne(x - bf16_tof(h));
}

// ---------------- prep: transpose V (bh, key, 128) -> Vt (bh, 128, NK) + split ----------------
__global__ __launch_bounds__(256) void vtsplit_kernel(const float* __restrict__ srcA,
        const float* __restrict__ srcB, ushort_t* __restrict__ hi, ushort_t* __restrict__ lo, int NK) {
    __shared__ float T[64][132];
    int bh = blockIdx.x, kt = blockIdx.y, t = threadIdx.x;
    for (int i = t; i < 2048; i += 256) {
        int r = i >> 5, c4 = (i & 31) << 2;
        int key = (kt << 6) + r;
        const float* s = (key < 512) ? (srcA + ((size_t)bh * 512 + key) * 128 + c4)
                                     : (srcB + ((size_t)bh * 512 + (key - 512)) * 128 + c4);
        *(float4*)&T[r][c4] = ld4(s);
    }
    __syncthreads();
    for (int i = t; i < 1024; i += 256) {
        int vc = i >> 3, kk = (i & 7) << 3;
        us8 h8, l8;
#pragma unroll
        for (int j = 0; j < 8; ++j) {
            float x = T[kk + j][vc];
            unsigned short hh = bf16_rne(x);
            h8[j] = hh; l8[j] = bf16_rne(x - bf16_tof(hh));
        }
        size_t off = ((size_t)bh * 128 + vc) * NK + (kt << 6) + kk;
        *(us8*)(hi + off) = h8;
        *(us8*)(lo + off) = l8;
    }
}

// ---------------- prep: cache bias ----------------
__global__ __launch_bounds__(256) void cbias_kernel(const float* __restrict__ al, float* __restrict__ cb) {
    int idx = blockIdx.x * 256 + threadIdx.x;           // 32768
    float v = al[idx];
    cb[idx] = (v > 0.0f) ? __logf(fmaxf(v, 1e-30f)) : -INF30;
}

// ---------------- wave-autonomous fused MFMA attention ----------------
// 512 blocks x 4 waves; each wave owns one 16-row q-tile of one bh and iterates
// all keys (seg0=xl 512, seg1=cache 512, seg2=current causal). NO __syncthreads.
#define GSTR 50
#define PSTR 40
__global__ __launch_bounds__(256) void attn3_kernel(
        const ushort_t* __restrict__ Qu_hi, const ushort_t* __restrict__ Qu_lo,
        const ushort_t* __restrict__ Qv_hi,
        const ushort_t* __restrict__ K_hi,  const ushort_t* __restrict__ K_lo,
        const ushort_t* __restrict__ C_hi,  const ushort_t* __restrict__ C_lo,
        const ushort_t* __restrict__ Vt_hi, const ushort_t* __restrict__ Vt_lo,
        const ushort_t* __restrict__ At_hi, const ushort_t* __restrict__ At_lo,
        const ushort_t* __restrict__ R_hi,
        const float* __restrict__ cbias, const float* __restrict__ gbuf,
        float* __restrict__ wvg) {
    __shared__ float    Gls[4][16 * GSTR];
    __shared__ __align__(16) ushort_t Phs[4][16 * PSTR];
    __shared__ __align__(16) ushort_t Pls[4][16 * PSTR];

    int t = threadIdx.x;
    int wvid = t >> 6, ln = t & 63;
    int col = ln & 15, quad = ln >> 4;
    int bh = blockIdx.x >> 3;
    int tg = blockIdx.x & 7;
    int tile = tg + (wvid << 3);       // interleave for load balance
    int l0w = tile << 4;
    int h = bh & 7;
    int b = bh >> 3;

    float* G = Gls[wvid];
    ushort_t* Ph = Phs[wvid];
    ushort_t* Pl = Pls[wvid];

    // persistent A-frags
    bf16x8 quh[4], qul[4], qvh[4];
    {
        size_t base = ((size_t)bh * 512 + l0w + col) * 128 + quad * 8;
#pragma unroll
        for (int s = 0; s < 4; ++s) {
            quh[s] = ldb8(Qu_hi + base + 32 * s);
            qul[s] = ldb8(Qu_lo + base + 32 * s);
            qvh[s] = ldb8(Qv_hi + base + 32 * s);
        }
    }

    f32x4 O[8];
#pragma unroll
    for (int u = 0; u < 8; ++u) O[u] = (f32x4){0.f, 0.f, 0.f, 0.f};
    float mrun[4], lrun[4];
#pragma unroll
    for (int r = 0; r < 4; ++r) { mrun[r] = -INF30; lrun[r] = 0.0f; }

    for (int seg = 0; seg < 3; ++seg) {
        int nit = (seg == 2) ? ((l0w + 47) >> 5) : 16;
        for (int iter = 0; iter < nit; ++iter) {
            int w0 = iter << 5;

            // ---- rel G tiles (seg 0 and 2), single-bf16 ----
            if (seg != 1) {
                int jt0 = ((seg == 0) ? w0 : (512 + w0)) + 496 - l0w;
#pragma unroll
                for (int u = 0; u < 3; ++u) {
                    int j = jt0 + 16 * u + col;
                    j = (j > 1023) ? 1023 : j;
                    const ushort_t* rp = R_hi + ((size_t)(h << 10) + j) * 128 + quad * 8;
                    f32x4 acc = (f32x4){0.f, 0.f, 0.f, 0.f};
#pragma unroll
                    for (int s = 0; s < 4; ++s) acc = MFMA16(qvh[s], ldb8(rp + 32 * s), acc);
#pragma unroll
                    for (int r = 0; r < 4; ++r)
                        G[(4 * quad + r) * GSTR + 16 * u + col] = acc[r];
                }
            }

            // ---- scores: two 16-key tiles ----
            const ushort_t *khb, *klb;
            if (seg == 0)      { khb = K_hi + ((size_t)bh * 1024 + w0) * 128;
                                 klb = K_lo + ((size_t)bh * 1024 + w0) * 128; }
            else if (seg == 1) { khb = C_hi + ((size_t)(h << 9) + w0) * 128;
                                 klb = C_lo + ((size_t)(h << 9) + w0) * 128; }
            else               { khb = K_hi + ((size_t)bh * 1024 + 512 + w0) * 128;
                                 klb = K_lo + ((size_t)bh * 1024 + 512 + w0) * 128; }
            f32x4 S[2];
#pragma unroll
            for (int t2 = 0; t2 < 2; ++t2) {
                const ushort_t* kph = khb + (size_t)(16 * t2 + col) * 128 + quad * 8;
                const ushort_t* kpl = klb + (size_t)(16 * t2 + col) * 128 + quad * 8;
                bf16x8 bhf[4], blf[4];
#pragma unroll
                for (int s = 0; s < 4; ++s) { bhf[s] = ldb8(kph + 32 * s); blf[s] = ldb8(kpl + 32 * s); }
                f32x4 acc = (f32x4){0.f, 0.f, 0.f, 0.f};
#pragma unroll
                for (int s = 0; s < 4; ++s) {
                    acc = MFMA16(quh[s], bhf[s], acc);
                    acc = MFMA16(qul[s], bhf[s], acc);
                    acc = MFMA16(quh[s], blf[s], acc);
                }
                S[t2] = acc;
            }

            // ---- score fixup ----
            float bias0 = 0.f, bias1 = 0.f;
            if (seg == 1) {
                bias0 = cbias[(size_t)(bh << 9) + w0 + col];
                bias1 = cbias[(size_t)(bh << 9) + w0 + 16 + col];
            }
#pragma unroll
            for (int t2 = 0; t2 < 2; ++t2) {
#pragma unroll
                for (int r = 0; r < 4; ++r) {
                    int row = 4 * quad + r;
                    float sv = S[t2][r];
                    if (seg != 1) {
                        sv = (sv + G[row * GSTR + 16 * t2 + col + 15 - row]) * INV_TAU;
                        if (seg == 2 && (w0 + 16 * t2 + col > l0w + row)) sv = -INF30;
                    } else {
                        sv = sv * INV_TAU + ((t2 == 0) ? bias0 : bias1);
                    }
                    S[t2][r] = sv;
                }
            }

            // ---- online softmax (per-row, within 16-lane group) ----
#pragma unroll
            for (int r = 0; r < 4; ++r) {
                float mv = fmaxf(S[0][r], S[1][r]);
#pragma unroll
                for (int m = 8; m > 0; m >>= 1) mv = fmaxf(mv, __shfl_xor(mv, m));
                float mnew = fmaxf(mrun[r], mv);
                float alpha = __expf(mrun[r] - mnew);
                mrun[r] = mnew;
                float p0 = __expf(S[0][r] - mnew);
                float p1 = __expf(S[1][r] - mnew);
                float ps = p0 + p1;
#pragma unroll
                for (int m = 8; m > 0; m >>= 1) ps += __shfl_xor(ps, m);
                lrun[r] = lrun[r] * alpha + ps;
#pragma unroll
                for (int u = 0; u < 8; ++u) O[u][r] *= alpha;
                int row = 4 * quad + r;
                unsigned short h0 = bf16_rne(p0);
                Ph[row * PSTR + col] = h0;
                Pl[row * PSTR + col] = bf16_rne(p0 - bf16_tof(h0));
                unsigned short h1 = bf16_rne(p1);
                Ph[row * PSTR + 16 + col] = h1;
                Pl[row * PSTR + 16 + col] = bf16_rne(p1 - bf16_tof(h1));
            }

            // ---- P A-frags (K=32) ----
            bf16x8 pah = *(const bf16x8*)&Ph[col * PSTR + quad * 8];
            bf16x8 pal = *(const bf16x8*)&Pl[col * PSTR + quad * 8];

            // ---- PV ----
            const ushort_t *vh, *vl;
            size_t vstr;
            int wbase;
            if (seg == 0)      { vh = Vt_hi + ((size_t)bh << 17); vl = Vt_lo + ((size_t)bh << 17); vstr = 1024; wbase = w0; }
            else if (seg == 1) { vh = At_hi + ((size_t)bh << 16); vl = At_lo + ((size_t)bh << 16); vstr = 512;  wbase = w0; }
            else               { vh = Vt_hi + ((size_t)bh << 17); vl = Vt_lo + ((size_t)bh << 17); vstr = 1024; wbase = 512 + w0; }
#pragma unroll
            for (int u = 0; u < 8; ++u) {
                int vcol = 16 * u + col;
                const ushort_t* vph = vh + (size_t)vcol * vstr + wbase + quad * 8;
                const ushort_t* vpl = vl + (size_t)vcol * vstr + wbase + quad * 8;
                bf16x8 vbh = ldb8(vph);
                bf16x8 vbl = ldb8(vpl);
                O[u] = MFMA16(pah, vbh, O[u]);
                O[u] = MFMA16(pal, vbh, O[u]);
                O[u] = MFMA16(pah, vbl, O[u]);
            }
        }
    }

    // ---- epilogue: O/l * g -> wvg ----
    float inv[4];
#pragma unroll
    for (int r = 0; r < 4; ++r) inv[r] = 1.0f / lrun[r];
#pragma unroll
    for (int u = 0; u < 8; ++u) {
#pragma unroll
        for (int r = 0; r < 4; ++r) {
            int row = 4 * quad + r;
            size_t gi = ((size_t)b * 512 + l0w + row) * 1024 + (h << 7) + 16 * u + col;
            wvg[gi] = O[u][r] * inv[r] * gbuf[gi];
        }
    }
}

extern "C" void kernel_launch(void* const* d_in, const int* in_sizes, int n_in,
                              void* d_out, int out_size, void* d_ws, size_t ws_size,
                              hipStream_t stream) {
    const float* x_in  = (const float*)d_in[0];
    const float* xl_k  = (const float*)d_in[2];
    const float* xl_v  = (const float*)d_in[3];
    const float* agg_u = (const float*)d_in[4];
    const float* agg_l = (const float*)d_in[5];
    const float* W_q   = (const float*)d_in[6];
    const float* W_kvg = (const float*)d_in[7];
    const float* W_res = (const float*)d_in[8];
    const float* x_u   = (const float*)d_in[9];
    const float* x_v   = (const float*)d_in[10];
    const float* xl_r  = (const float*)d_in[11];
    const float* cbk   = (const float*)d_in[12];
    float* out = (float*)d_out;
    char* wb = (char*)d_ws;

    float*  x_t   = (float*)(wb);                       // 16 MB  [alias: K_hi]
    float*  qbuf  = (float*)(wb + 16777216ul);          // 16 MB  [alias: Vt_lo]
    float*  kbuf  = (float*)(wb + 33554432ul);          // 16 MB  [alias: Vt_hi]
    float*  vbuf  = (float*)(wb + 50331648ul);          // 16 MB  [alias: At_hi+At_lo]
    float*  gbuf  = (float*)(wb + 67108864ul);          // 16 MB
    float*  wvg   = (float*)(wb + 83886080ul);          // 16 MB
    float*  cT    = (float*)(wb + 100663296ul);         // 2 MB   [alias: C_hi+C_lo]
    float*  cnm   = (float*)(wb + 102760448ul);         // 16 KB
    ushort_t* Qu_hi = (ushort_t*)(wb + 102776832ul);    // 8 MB
    ushort_t* Qu_lo = (ushort_t*)(wb + 111165440ul);    // 8 MB
    ushort_t* Qv_hi = (ushort_t*)(wb + 119554048ul);    // 8 MB
    ushort_t* K_lo  = (ushort_t*)(wb + 136331264ul);    // 16 MB
    ushort_t* R_hi  = (ushort_t*)(wb + 153108480ul);    // 2 MB
    float*  cbias   = (float*)(wb + 157302784ul);       // 128 KB

    ushort_t* K_hi  = (ushort_t*)x_t;
    ushort_t* Vt_hi = (ushort_t*)kbuf;
    ushort_t* Vt_lo = (ushort_t*)qbuf;
    ushort_t* At_hi = (ushort_t*)vbuf;
    ushort_t* At_lo = (ushort_t*)(wb + 50331648ul + 8388608ul);
    ushort_t* C_hi  = (ushort_t*)cT;
    ushort_t* C_lo  = (ushort_t*)(wb + 100663296ul + 1048576ul);

    ln_dm_kernel<<<4096, 256, 0, stream>>>(x_in, x_t);
    gemm_kernel<<<dim3(16, 64), 256, 0, stream>>>(x_t, W_q, 1024, 0, qbuf, nullptr, nullptr);
    gemm_kernel<<<dim3(48, 64), 256, 0, stream>>>(x_t, W_kvg, 3072, 1, kbuf, vbuf, gbuf);
    ln128_kernel<<<16384, 256, 0, stream>>>(qbuf, kbuf);
    cbt_kernel<<<2048, 256, 0, stream>>>(cbk, cT);
    cnorm_kernel<<<1024, 256, 0, stream>>>(cbk, cnm);
    vq_kernel<<<2048, 256, 0, stream>>>(kbuf, cT, cnm, cbk);
    // prep splits
    split_q_kernel<<<16384, 256, 0, stream>>>(qbuf, x_u, x_v, Qu_hi, Qu_lo, Qv_hi);
    split_koff_kernel<<<16384, 256, 0, stream>>>(xl_k, K_hi, K_lo, 0);
    split_koff_kernel<<<16384, 256, 0, stream>>>(kbuf, K_hi, K_lo, 512);
    split_plain_kernel<<<2048, 256, 0, stream>>>(cbk, C_hi, C_lo);
    cvt_hi_kernel<<<4096, 256, 0, stream>>>(xl_r, R_hi);
    vtsplit_kernel<<<dim3(64, 16), 256, 0, stream>>>(xl_v, vbuf, Vt_hi, Vt_lo, 1024);
    vtsplit_kernel<<<dim3(64, 8), 256, 0, stream>>>(agg_u, agg_u, At_hi, At_lo, 512);
    cbias_kernel<<<128, 256, 0, stream>>>(agg_l, cbias);
    // wave-autonomous fused attention
    attn3_kernel<<<512, 256, 0, stream>>>(Qu_hi, Qu_lo, Qv_hi, K_hi, K_lo, C_hi, C_lo,
                                          Vt_hi, Vt_lo, At_hi, At_lo, R_hi,
                                          cbias, gbuf, wvg);
    gemm_kernel<<<dim3(16, 64), 256, 0, stream>>>(wvg, W_res, 1024, 2, out, nullptr, nullptr);
}

// Round 4
// 1035.414 us; speedup vs baseline: 2.9808x; 1.2622x over previous
//
#include <hip/hip_runtime.h>

#define INF30 1e30f
#define INV_TAU 0.08838834764831845f

typedef unsigned short ushort_t;
typedef __attribute__((ext_vector_type(8))) short bf16x8;
typedef __attribute__((ext_vector_type(4))) float f32x4;
typedef __attribute__((ext_vector_type(8))) unsigned short us8;

__device__ __forceinline__ float4 ld4(const float* p) { return *(const float4*)p; }

__device__ __forceinline__ unsigned short bf16_rne(float x) {
    unsigned int u = __float_as_uint(x);
    unsigned int r = u + 0x7fffu + ((u >> 16) & 1u);
    return (unsigned short)(r >> 16);
}
__device__ __forceinline__ float bf16_tof(unsigned short h) {
    return __uint_as_float(((unsigned int)h) << 16);
}
__device__ __forceinline__ bf16x8 ldb8(const ushort_t* p) { return *(const bf16x8*)p; }

#define MFMA16(a, b, c) __builtin_amdgcn_mfma_f32_16x16x32_bf16((a), (b), (c), 0, 0, 0)

// ---------------- LayerNorm over DM=1024 ----------------
__global__ __launch_bounds__(256) void ln_dm_kernel(const float* __restrict__ x, float* __restrict__ y) {
    size_t row = blockIdx.x;
    const float4* xr = (const float4*)(x + row * 1024);
    float4 v = xr[threadIdx.x];
    float s  = v.x + v.y + v.z + v.w;
    float ss = v.x*v.x + v.y*v.y + v.z*v.z + v.w*v.w;
#pragma unroll
    for (int off = 32; off > 0; off >>= 1) {
        s  += __shfl_down(s, off);
        ss += __shfl_down(ss, off);
    }
    __shared__ float rs[4], rss[4];
    int wv = threadIdx.x >> 6, ln = threadIdx.x & 63;
    if (ln == 0) { rs[wv] = s; rss[wv] = ss; }
    __syncthreads();
    s  = rs[0] + rs[1] + rs[2] + rs[3];
    ss = rss[0] + rss[1] + rss[2] + rss[3];
    float mu  = s * (1.0f/1024.0f);
    float var = ss * (1.0f/1024.0f) - mu*mu;
    float r = rsqrtf(var + 1e-6f);
    float4 o;
    o.x = (v.x - mu) * r; o.y = (v.y - mu) * r; o.z = (v.z - mu) * r; o.w = (v.w - mu) * r;
    ((float4*)(y + row * 1024))[threadIdx.x] = o;
}

// ---------------- fp32 tiled GEMM (k-columns only: argmin-critical path) ----------------
__global__ __launch_bounds__(256) void gemm_kernel(const float* __restrict__ A, const float* __restrict__ W,
                                                   int N, int mode,
                                                   float* __restrict__ o0, float* __restrict__ o1,
                                                   float* __restrict__ o2) {
    __shared__ float As[16][64];
    __shared__ float Bs[16][64];
    int t = threadIdx.x;
    int col0 = blockIdx.x << 6;
    int row0 = blockIdx.y << 6;
    int tx = t & 15, ty = t >> 4;
    int arow = t >> 2, akq = t & 3;
    int bkr = t >> 4, bcq = t & 15;
    const float* Ap = A + (size_t)(row0 + arow) * 1024 + akq * 4;
    const float* Wp = W + (size_t)bkr * N + col0 + bcq * 4;
    float acc[4][4];
#pragma unroll
    for (int i = 0; i < 4; ++i)
#pragma unroll
        for (int j = 0; j < 4; ++j) acc[i][j] = 0.0f;

    for (int kt = 0; kt < 64; ++kt) {
        float4 a4 = ld4(Ap + kt * 16);
        float4 b4 = ld4(Wp + (size_t)kt * 16 * N);
        __syncthreads();
        As[akq*4+0][arow] = a4.x;
        As[akq*4+1][arow] = a4.y;
        As[akq*4+2][arow] = a4.z;
        As[akq*4+3][arow] = a4.w;
        *(float4*)&Bs[bkr][bcq*4] = b4;
        __syncthreads();
#pragma unroll
        for (int kk = 0; kk < 16; ++kk) {
            float4 av = *(float4*)&As[kk][ty*4];
            float4 bv = *(float4*)&Bs[kk][tx*4];
            acc[0][0] += av.x*bv.x; acc[0][1] += av.x*bv.y; acc[0][2] += av.x*bv.z; acc[0][3] += av.x*bv.w;
            acc[1][0] += av.y*bv.x; acc[1][1] += av.y*bv.y; acc[1][2] += av.y*bv.z; acc[1][3] += av.y*bv.w;
            acc[2][0] += av.z*bv.x; acc[2][1] += av.z*bv.y; acc[2][2] += av.z*bv.z; acc[2][3] += av.z*bv.w;
            acc[3][0] += av.w*bv.x; acc[3][1] += av.w*bv.y; acc[3][2] += av.w*bv.z; acc[3][3] += av.w*bv.w;
        }
    }

#pragma unroll
    for (int i = 0; i < 4; ++i) {
        int rr = row0 + ty*4 + i;
        int b = rr >> 9, l = rr & 511;
#pragma unroll
        for (int j = 0; j < 4; ++j) {
            int cc = col0 + tx*4 + j;
            float vv = acc[i][j];
            if (mode == 0) {
                o0[((size_t)((b<<3) + (cc>>7)) * 512 + l) * 128 + (cc & 127)] = vv;
            } else if (mode == 1) {
                if (cc < 1024) {
                    o0[((size_t)((b<<3) + (cc>>7)) * 512 + l) * 128 + (cc & 127)] = vv;
                } else if (cc < 2048) {
                    int c2 = cc - 1024;
                    o1[((size_t)((b<<3) + (c2>>7)) * 512 + l) * 128 + (c2 & 127)] = vv;
                } else {
                    o2[(size_t)rr * 1024 + (cc - 2048)] = vv / (1.0f + __expf(-vv));
                }
            } else {
                o0[(size_t)rr * 1024 + cc] = vv;
            }
        }
    }
}

// ---------------- weight transpose + bf16 hi/lo split: W[K=1024][Ntot] cols [c0,c0+N) -> Wt[N][1024] ----------------
__global__ __launch_bounds__(256) void wtsplit_kernel(const float* __restrict__ W, int Ntot, int c0,
                                                      ushort_t* __restrict__ th, ushort_t* __restrict__ tl) {
    __shared__ float T[64][68];
    int n0 = blockIdx.x << 6, k0 = blockIdx.y << 6, t = threadIdx.x;
    for (int i = t; i < 1024; i += 256) {
        int kk = i >> 4, nn4 = (i & 15) << 2;
        *(float4*)&T[kk][nn4] = ld4(W + (size_t)(k0 + kk) * Ntot + c0 + n0 + nn4);
    }
    __syncthreads();
    for (int i = t; i < 512; i += 256) {
        int nn = i >> 3, kc = (i & 7) << 3;
        us8 h8, l8;
#pragma unroll
        for (int j = 0; j < 8; ++j) {
            float x = T[kc + j][nn];
            unsigned short hh = bf16_rne(x);
            h8[j] = hh; l8[j] = bf16_rne(x - bf16_tof(hh));
        }
        size_t off = (size_t)(n0 + nn) * 1024 + k0 + kc;
        *(us8*)(th + off) = h8;
        *(us8*)(tl + off) = l8;
    }
}

// ---------------- bf16 3-term split GEMM: C[4096,N] = A[4096,1024] @ Wt^T ----------------
// mode 0: scatter to (B,H,L,128); mode 1: cc<1024 -> v scatter, else silu -> o1; mode 2: row-major
#define GSTRIDE 40
__global__ __launch_bounds__(256) void gemm_bf16_kernel(
        const ushort_t* __restrict__ Ah, const ushort_t* __restrict__ Al,
        const ushort_t* __restrict__ Bth, const ushort_t* __restrict__ Btl,
        int mode, float* __restrict__ o0, float* __restrict__ o1) {
    __shared__ ushort_t LA[2][128 * GSTRIDE];
    __shared__ ushort_t LB[2][128 * GSTRIDE];
    int t = threadIdx.x;
    int col0 = blockIdx.x << 7, row0 = blockIdx.y << 7;
    int wvid = t >> 6, ln = t & 63;
    int lcol = ln & 15, quad = ln >> 4;
    int qm = wvid >> 1, qn = wvid & 1;

    f32x4 C[4][4];
#pragma unroll
    for (int i = 0; i < 4; ++i)
#pragma unroll
        for (int j = 0; j < 4; ++j) C[i][j] = (f32x4){0.f, 0.f, 0.f, 0.f};

    for (int k0 = 0; k0 < 1024; k0 += 32) {
        us8 ra[2][2], rb[2][2];
#pragma unroll
        for (int v = 0; v < 2; ++v) {
            int cid = t + 256 * v;
            int row = cid >> 2, ch = cid & 3;
            size_t ga = (size_t)(row0 + row) * 1024 + k0 + ch * 8;
            size_t gb = (size_t)(col0 + row) * 1024 + k0 + ch * 8;
            ra[v][0] = *(const us8*)(Ah + ga);
            ra[v][1] = *(const us8*)(Al + ga);
            rb[v][0] = *(const us8*)(Bth + gb);
            rb[v][1] = *(const us8*)(Btl + gb);
        }
        __syncthreads();
#pragma unroll
        for (int v = 0; v < 2; ++v) {
            int cid = t + 256 * v;
            int row = cid >> 2, ch = cid & 3;
            *(us8*)&LA[0][row * GSTRIDE + ch * 8] = ra[v][0];
            *(us8*)&LA[1][row * GSTRIDE + ch * 8] = ra[v][1];
            *(us8*)&LB[0][row * GSTRIDE + ch * 8] = rb[v][0];
            *(us8*)&LB[1][row * GSTRIDE + ch * 8] = rb[v][1];
        }
        __syncthreads();
        bf16x8 afh[4], afl[4], bfh[4], bfl[4];
#pragma unroll
        for (int i = 0; i < 4; ++i) {
            int r = qm * 64 + i * 16 + lcol;
            afh[i] = *(const bf16x8*)&LA[0][r * GSTRIDE + quad * 8];
            afl[i] = *(const bf16x8*)&LA[1][r * GSTRIDE + quad * 8];
            int c = qn * 64 + i * 16 + lcol;
            bfh[i] = *(const bf16x8*)&LB[0][c * GSTRIDE + quad * 8];
            bfl[i] = *(const bf16x8*)&LB[1][c * GSTRIDE + quad * 8];
        }
#pragma unroll
        for (int i = 0; i < 4; ++i)
#pragma unroll
            for (int j = 0; j < 4; ++j) {
                C[i][j] = MFMA16(afh[i], bfh[j], C[i][j]);
                C[i][j] = MFMA16(afl[i], bfh[j], C[i][j]);
                C[i][j] = MFMA16(afh[i], bfl[j], C[i][j]);
            }
    }

#pragma unroll
    for (int i = 0; i < 4; ++i) {
#pragma unroll
        for (int r = 0; r < 4; ++r) {
            int rr = row0 + qm * 64 + 16 * i + quad * 4 + r;
            int b = rr >> 9, l = rr & 511;
#pragma unroll
            for (int j = 0; j < 4; ++j) {
                int cc = col0 + qn * 64 + 16 * j + lcol;
                float vv = C[i][j][r];
                if (mode == 0) {
                    o0[((size_t)((b<<3) + (cc>>7)) * 512 + l) * 128 + (cc & 127)] = vv;
                } else if (mode == 1) {
                    if (cc < 1024) o0[((size_t)((b<<3) + (cc>>7)) * 512 + l) * 128 + (cc & 127)] = vv;
                    else o1[(size_t)rr * 1024 + (cc - 1024)] = vv / (1.0f + __expf(-vv));
                } else {
                    o0[(size_t)rr * 1024 + cc] = vv;
                }
            }
        }
    }
}

// ---------------- LayerNorm over last dim 128 for q and k, in place ----------------
__global__ __launch_bounds__(256) void ln128_kernel(float* __restrict__ qb, float* __restrict__ kb) {
    int wv = threadIdx.x >> 6, ln = threadIdx.x & 63;
    int gw = (blockIdx.x << 2) + wv;
    float* base = (gw < 32768) ? qb : kb;
    int row = gw & 32767;
    float2 x = *(float2*)(base + (size_t)row * 128 + (ln << 1));
    float s  = x.x + x.y;
    float ss = x.x*x.x + x.y*x.y;
#pragma unroll
    for (int m = 32; m > 0; m >>= 1) { s += __shfl_xor(s, m); ss += __shfl_xor(ss, m); }
    float mu  = s * (1.0f/128.0f);
    float var = ss * (1.0f/128.0f) - mu*mu;
    float r = rsqrtf(var + 1e-6f);
    x.x = (x.x - mu) * r; x.y = (x.y - mu) * r;
    *(float2*)(base + (size_t)row * 128 + (ln << 1)) = x;
}

// ---------------- codebook transpose + norms ----------------
__global__ __launch_bounds__(256) void cbt_kernel(const float* __restrict__ cb, float* __restrict__ cT) {
    int idx = blockIdx.x * 256 + threadIdx.x;
    int h = idx >> 16, s = (idx >> 7) & 511, d = idx & 127;
    cT[((size_t)((h << 7) + d)) * 512 + s] = cb[idx];
}

__global__ __launch_bounds__(256) void cnorm_kernel(const float* __restrict__ cb, float* __restrict__ cn) {
    int wv = threadIdx.x >> 6, ln = threadIdx.x & 63;
    int row = (blockIdx.x << 2) + wv;
    float2 x = *(const float2*)(cb + (size_t)row * 128 + (ln << 1));
    float ss = x.x*x.x + x.y*x.y;
#pragma unroll
    for (int m = 32; m > 0; m >>= 1) ss += __shfl_xor(ss, m);
    if (ln == 0) cn[row] = ss;
}

// ---------------- VQ argmin (fp32, unchanged) ----------------
__global__ __launch_bounds__(256) void vq_kernel(float* __restrict__ kb, const float* __restrict__ cT,
                                                 const float* __restrict__ cn, const float* __restrict__ cb) {
    __shared__ float sK[4][4][128];
    int wv = threadIdx.x >> 6, ln = threadIdx.x & 63;
    int gw = (blockIdx.x << 2) + wv;
    int bh = gw >> 7;
    int l4 = (gw & 127) << 2;
    int h = bh & 7;
    size_t r0 = ((size_t)bh << 9) + l4;
#pragma unroll
    for (int i = 0; i < 4; ++i) {
        float2 kx = *(const float2*)(kb + (r0 + i) * 128 + (ln << 1));
        sK[wv][i][(ln<<1)]   = kx.x;
        sK[wv][i][(ln<<1)+1] = kx.y;
    }
    __syncthreads();
    const float* ct = cT + ((size_t)h << 7) * 512;
    int s0 = ln << 3;
    float dt[4][8];
#pragma unroll
    for (int i = 0; i < 4; ++i)
#pragma unroll
        for (int j = 0; j < 8; ++j) dt[i][j] = 0.0f;

    for (int dc = 0; dc < 4; ++dc) {
        float ch[4][8];
#pragma unroll
        for (int i = 0; i < 4; ++i)
#pragma unroll
            for (int j = 0; j < 8; ++j) ch[i][j] = 0.0f;
#pragma unroll 4
        for (int d = dc * 32; d < dc * 32 + 32; ++d) {
            float4 c0 = ld4(ct + (size_t)d * 512 + s0);
            float4 c1 = ld4(ct + (size_t)d * 512 + s0 + 4);
#pragma unroll
            for (int i = 0; i < 4; ++i) {
                float kd = sK[wv][i][d];
                ch[i][0] += kd * c0.x; ch[i][1] += kd * c0.y; ch[i][2] += kd * c0.z; ch[i][3] += kd * c0.w;
                ch[i][4] += kd * c1.x; ch[i][5] += kd * c1.y; ch[i][6] += kd * c1.z; ch[i][7] += kd * c1.w;
            }
        }
#pragma unroll
        for (int i = 0; i < 4; ++i)
#pragma unroll
            for (int j = 0; j < 8; ++j) dt[i][j] += ch[i][j];
    }
    const float* cnh = cn + (h << 9);
#pragma unroll
    for (int i = 0; i < 4; ++i) {
        float bestv = cnh[s0] - 2.0f * dt[i][0];
        int bestz = s0;
#pragma unroll
        for (int j = 1; j < 8; ++j) {
            float scv = cnh[s0 + j] - 2.0f * dt[i][j];
            if (scv < bestv) { bestv = scv; bestz = s0 + j; }
        }
#pragma unroll
        for (int m = 32; m > 0; m >>= 1) {
            float ov = __shfl_xor(bestv, m);
            int   oz = __shfl_xor(bestz, m);
            if (ov < bestv || (ov == bestv && oz < bestz)) { bestv = ov; bestz = oz; }
        }
        float2 cz = *(const float2*)(cb + ((size_t)(h << 9) + bestz) * 128 + (ln << 1));
        *(float2*)(kb + (r0 + i) * 128 + (ln << 1)) = cz;
    }
}

// ---------------- prep kernels ----------------
__global__ __launch_bounds__(256) void split_q_kernel(const float* __restrict__ q,
        const float* __restrict__ xu, const float* __restrict__ xv,
        ushort_t* __restrict__ quh, ushort_t* __restrict__ qul,
        ushort_t* __restrict__ qvh) {
    int idx = blockIdx.x * 256 + threadIdx.x;
    int d = idx & 127;
    int h = (idx >> 16) & 7;
    float qv = q[idx];
    float a = qv + xu[(h << 7) + d];
    unsigned short ah = bf16_rne(a);
    quh[idx] = ah; qul[idx] = bf16_rne(a - bf16_tof(ah));
    float b = qv + xv[(h << 7) + d];
    qvh[idx] = bf16_rne(b);
}

__global__ __launch_bounds__(256) void split_plain_kernel(const float* __restrict__ src,
        ushort_t* __restrict__ hi, ushort_t* __restrict__ lo) {
    int idx = blockIdx.x * 256 + threadIdx.x;
    float x = src[idx];
    unsigned short h = bf16_rne(x);
    hi[idx] = h; lo[idx] = bf16_rne(x - bf16_tof(h));
}

__global__ __launch_bounds__(256) void cvt_hi_kernel(const float* __restrict__ src,
        ushort_t* __restrict__ hi) {
    int idx = blockIdx.x * 256 + threadIdx.x;
    hi[idx] = bf16_rne(src[idx]);
}

__global__ __launch_bounds__(256) void split_koff_kernel(const float* __restrict__ src,
        ushort_t* __restrict__ hi, ushort_t* __restrict__ lo, int rowoff) {
    int idx = blockIdx.x * 256 + threadIdx.x;
    int bh = idx >> 16, rem = idx & 65535;
    size_t dst = ((size_t)bh << 17) + ((size_t)rowoff << 7) + rem;
    float x = src[idx];
    unsigned short h = bf16_rne(x);
    hi[dst] = h; lo[dst] = bf16_rne(x - bf16_tof(h));
}

__global__ __launch_bounds__(256) void vtsplit_kernel(const float* __restrict__ srcA,
        const float* __restrict__ srcB, ushort_t* __restrict__ hi, ushort_t* __restrict__ lo, int NK) {
    __shared__ float T[64][132];
    int bh = blockIdx.x, kt = blockIdx.y, t = threadIdx.x;
    for (int i = t; i < 2048; i += 256) {
        int r = i >> 5, c4 = (i & 31) << 2;
        int key = (kt << 6) + r;
        const float* s = (key < 512) ? (srcA + ((size_t)bh * 512 + key) * 128 + c4)
                                     : (srcB + ((size_t)bh * 512 + (key - 512)) * 128 + c4);
        *(float4*)&T[r][c4] = ld4(s);
    }
    __syncthreads();
    for (int i = t; i < 1024; i += 256) {
        int vc = i >> 3, kk = (i & 7) << 3;
        us8 h8, l8;
#pragma unroll
        for (int j = 0; j < 8; ++j) {
            float x = T[kk + j][vc];
            unsigned short hh = bf16_rne(x);
            h8[j] = hh; l8[j] = bf16_rne(x - bf16_tof(hh));
        }
        size_t off = ((size_t)bh * 128 + vc) * NK + (kt << 6) + kk;
        *(us8*)(hi + off) = h8;
        *(us8*)(lo + off) = l8;
    }
}

__global__ __launch_bounds__(256) void cbias_kernel(const float* __restrict__ al, float* __restrict__ cb) {
    int idx = blockIdx.x * 256 + threadIdx.x;
    float v = al[idx];
    cb[idx] = (v > 0.0f) ? __logf(fmaxf(v, 1e-30f)) : -INF30;
}

// ---------------- split-K wave-autonomous MFMA attention ----------------
// 1024 blocks x 4 waves. Block handles tiles (tg, tg+16) of one bh; waves {0,1}
// split tile tg's key stream, waves {2,3} split tile tg+16's. One barrier total.
#define PSTR 40
__global__ __launch_bounds__(256) void attn4_kernel(
        const ushort_t* __restrict__ Qu_hi, const ushort_t* __restrict__ Qu_lo,
        const ushort_t* __restrict__ Qv_hi,
        const ushort_t* __restrict__ K_hi,  const ushort_t* __restrict__ K_lo,
        const ushort_t* __restrict__ C_hi,  const ushort_t* __restrict__ C_lo,
        const ushort_t* __restrict__ Vt_hi, const ushort_t* __restrict__ Vt_lo,
        const ushort_t* __restrict__ At_hi, const ushort_t* __restrict__ At_lo,
        const ushort_t* __restrict__ R_hi,
        const float* __restrict__ cbias, const float* __restrict__ gbuf,
        float* __restrict__ wvg) {
    __shared__ __align__(16) ushort_t Phs[4][16 * PSTR];
    __shared__ __align__(16) ushort_t Pls[4][16 * PSTR];
    __shared__ float Oc[2][16 * 132];
    __shared__ float mc[2][16], lc[2][16];

    int t = threadIdx.x;
    int wvid = t >> 6, ln = t & 63;
    int col = ln & 15, quad = ln >> 4;
    int bh = blockIdx.x >> 4;
    int tg = blockIdx.x & 15;
    int tile = (wvid & 2) ? (tg + 16) : tg;
    int q = wvid & 1;
    int l0w = tile << 4;
    int h = bh & 7;
    int b = bh >> 3;

    ushort_t* Ph = Phs[wvid];
    ushort_t* Pl = Pls[wvid];

    // persistent A-frags
    bf16x8 quh[4], qul[4], qvh[4];
    {
        size_t base = ((size_t)bh * 512 + l0w + col) * 128 + quad * 8;
#pragma unroll
        for (int s = 0; s < 4; ++s) {
            quh[s] = ldb8(Qu_hi + base + 32 * s);
            qul[s] = ldb8(Qu_lo + base + 32 * s);
            qvh[s] = ldb8(Qv_hi + base + 32 * s);
        }
    }

    f32x4 O[8];
#pragma unroll
    for (int u = 0; u < 8; ++u) O[u] = (f32x4){0.f, 0.f, 0.f, 0.f};
    float mrun[4], lrun[4];
#pragma unroll
    for (int r = 0; r < 4; ++r) { mrun[r] = -INF30; lrun[r] = 0.0f; }

    int nt2 = (l0w + 47) >> 5;
    int T = 32 + nt2;
    int half = (T + 1) >> 1;
    int ti0 = q ? half : 0;
    int ti1 = q ? T : half;

    for (int ti = ti0; ti < ti1; ++ti) {
        int seg, w0;
        if (ti < 16)      { seg = 0; w0 = ti << 5; }
        else if (ti < 32) { seg = 1; w0 = (ti - 16) << 5; }
        else              { seg = 2; w0 = (ti - 32) << 5; }

        // ---- rel G tiles in registers (seg 0/2) ----
        f32x4 Gacc[3];
        if (seg != 1) {
            int jt0 = ((seg == 0) ? w0 : (512 + w0)) + 496 - l0w;
#pragma unroll
            for (int u = 0; u < 3; ++u) {
                int j = jt0 + 16 * u + col;
                j = (j > 1023) ? 1023 : j;
                const ushort_t* rp = R_hi + ((size_t)(h << 10) + j) * 128 + quad * 8;
                f32x4 acc = (f32x4){0.f, 0.f, 0.f, 0.f};
#pragma unroll
                for (int s = 0; s < 4; ++s) acc = MFMA16(qvh[s], ldb8(rp + 32 * s), acc);
                Gacc[u] = acc;
            }
        }

        // ---- scores: two 16-key tiles ----
        const ushort_t *khb, *klb;
        if (seg == 0)      { khb = K_hi + ((size_t)bh * 1024 + w0) * 128;
                             klb = K_lo + ((size_t)bh * 1024 + w0) * 128; }
        else if (seg == 1) { khb = C_hi + ((size_t)(h << 9) + w0) * 128;
                             klb = C_lo + ((size_t)(h << 9) + w0) * 128; }
        else               { khb = K_hi + ((size_t)bh * 1024 + 512 + w0) * 128;
                             klb = K_lo + ((size_t)bh * 1024 + 512 + w0) * 128; }
        f32x4 S[2];
#pragma unroll
        for (int t2 = 0; t2 < 2; ++t2) {
            const ushort_t* kph = khb + (size_t)(16 * t2 + col) * 128 + quad * 8;
            const ushort_t* kpl = klb + (size_t)(16 * t2 + col) * 128 + quad * 8;
            bf16x8 bhf[4], blf[4];
#pragma unroll
            for (int s = 0; s < 4; ++s) { bhf[s] = ldb8(kph + 32 * s); blf[s] = ldb8(kpl + 32 * s); }
            f32x4 acc = (f32x4){0.f, 0.f, 0.f, 0.f};
#pragma unroll
            for (int s = 0; s < 4; ++s) {
                acc = MFMA16(quh[s], bhf[s], acc);
                acc = MFMA16(qul[s], bhf[s], acc);
                acc = MFMA16(quh[s], blf[s], acc);
            }
            S[t2] = acc;
        }

        // ---- score fixup ----
        float bias0 = 0.f, bias1 = 0.f;
        if (seg == 1) {
            bias0 = cbias[(size_t)(bh << 9) + w0 + col];
            bias1 = cbias[(size_t)(bh << 9) + w0 + 16 + col];
        }
#pragma unroll
        for (int t2 = 0; t2 < 2; ++t2) {
#pragma unroll
            for (int r = 0; r < 4; ++r) {
                int row = 4 * quad + r;
                float sv = S[t2][r];
                if (seg != 1) {
                    int d = col + 15 - row;           // 0..30
                    int src = quad * 16 + (d & 15);
                    float g0 = __shfl(Gacc[t2][r], src);
                    float g1 = __shfl(Gacc[t2 + 1][r], src);
                    float gv = (d >= 16) ? g1 : g0;
                    sv = (sv + gv) * INV_TAU;
                    if (seg == 2 && (w0 + 16 * t2 + col > l0w + row)) sv = -INF30;
                } else {
                    sv = sv * INV_TAU + ((t2 == 0) ? bias0 : bias1);
                }
                S[t2][r] = sv;
            }
        }

        // ---- online softmax ----
#pragma unroll
        for (int r = 0; r < 4; ++r) {
            float mv = fmaxf(S[0][r], S[1][r]);
#pragma unroll
            for (int m = 8; m > 0; m >>= 1) mv = fmaxf(mv, __shfl_xor(mv, m));
            float mnew = fmaxf(mrun[r], mv);
            float alpha = __expf(mrun[r] - mnew);
            mrun[r] = mnew;
            float p0 = __expf(S[0][r] - mnew);
            float p1 = __expf(S[1][r] - mnew);
            float ps = p0 + p1;
#pragma unroll
            for (int m = 8; m > 0; m >>= 1) ps += __shfl_xor(ps, m);
            lrun[r] = lrun[r] * alpha + ps;
#pragma unroll
            for (int u = 0; u < 8; ++u) O[u][r] *= alpha;
            int row = 4 * quad + r;
            unsigned short h0 = bf16_rne(p0);
            Ph[row * PSTR + col] = h0;
            Pl[row * PSTR + col] = bf16_rne(p0 - bf16_tof(h0));
            unsigned short h1 = bf16_rne(p1);
            Ph[row * PSTR + 16 + col] = h1;
            Pl[row * PSTR + 16 + col] = bf16_rne(p1 - bf16_tof(h1));
        }

        bf16x8 pah = *(const bf16x8*)&Ph[col * PSTR + quad * 8];
        bf16x8 pal = *(const bf16x8*)&Pl[col * PSTR + quad * 8];

        // ---- PV ----
        const ushort_t *vh, *vl;
        size_t vstr;
        int wbase;
        if (seg == 0)      { vh = Vt_hi + ((size_t)bh << 17); vl = Vt_lo + ((size_t)bh << 17); vstr = 1024; wbase = w0; }
        else if (seg == 1) { vh = At_hi + ((size_t)bh << 16); vl = At_lo + ((size_t)bh << 16); vstr = 512;  wbase = w0; }
        else               { vh = Vt_hi + ((size_t)bh << 17); vl = Vt_lo + ((size_t)bh << 17); vstr = 1024; wbase = 512 + w0; }
#pragma unroll
        for (int u = 0; u < 8; ++u) {
            int vcol = 16 * u + col;
            bf16x8 vbh = ldb8(vh + (size_t)vcol * vstr + wbase + quad * 8);
            bf16x8 vbl = ldb8(vl + (size_t)vcol * vstr + wbase + quad * 8);
            O[u] = MFMA16(pah, vbh, O[u]);
            O[u] = MFMA16(pal, vbh, O[u]);
            O[u] = MFMA16(pah, vbl, O[u]);
        }
    }

    // ---- split-K combine ----
    if (q) {
        int i = wvid >> 1;
#pragma unroll
        for (int u = 0; u < 8; ++u)
#pragma unroll
            for (int r = 0; r < 4; ++r)
                Oc[i][(quad * 4 + r) * 132 + 16 * u + col] = O[u][r];
        if (col == 0) {
#pragma unroll
            for (int r = 0; r < 4; ++r) {
                mc[i][quad * 4 + r] = mrun[r];
                lc[i][quad * 4 + r] = lrun[r];
            }
        }
    }
    __syncthreads();
    if (!q) {
        int i = wvid >> 1;
#pragma unroll
        for (int r = 0; r < 4; ++r) {
            int row = quad * 4 + r;
            float m1 = mc[i][row], l1 = lc[i][row];
            float mm = fmaxf(mrun[r], m1);
            float a0 = __expf(mrun[r] - mm);
            float a1 = __expf(m1 - mm);
            float linv = 1.0f / (lrun[r] * a0 + l1 * a1);
#pragma unroll
            for (int u = 0; u < 8; ++u) {
                size_t gi = ((size_t)b * 512 + l0w + row) * 1024 + (h << 7) + 16 * u + col;
                float val = (O[u][r] * a0 + Oc[i][row * 132 + 16 * u + col] * a1) * linv;
                wvg[gi] = val * gbuf[gi];
            }
        }
    }
}

extern "C" void kernel_launch(void* const* d_in, const int* in_sizes, int n_in,
                              void* d_out, int out_size, void* d_ws, size_t ws_size,
                              hipStream_t stream) {
    const float* x_in  = (const float*)d_in[0];
    const float* xl_k  = (const float*)d_in[2];
    const float* xl_v  = (const float*)d_in[3];
    const float* agg_u = (const float*)d_in[4];
    const float* agg_l = (const float*)d_in[5];
    const float* W_q   = (const float*)d_in[6];
    const float* W_kvg = (const float*)d_in[7];
    const float* W_res = (const float*)d_in[8];
    const float* x_u   = (const float*)d_in[9];
    const float* x_v   = (const float*)d_in[10];
    const float* xl_r  = (const float*)d_in[11];
    const float* cbk   = (const float*)d_in[12];
    float* out = (float*)d_out;
    char* wb = (char*)d_ws;

    float*  x_t   = (float*)(wb);                       // 16 MB [alias: K_hi; later Awh/Awl]
    float*  qbuf  = (float*)(wb + 16777216ul);          // 16 MB [alias: Vt_lo]
    float*  kbuf  = (float*)(wb + 33554432ul);          // 16 MB [alias: Vt_hi]
    float*  vbuf  = (float*)(wb + 50331648ul);          // 16 MB [alias: At_hi+At_lo]
    float*  gbuf  = (float*)(wb + 67108864ul);          // 16 MB
    float*  wvg   = (float*)(wb + 83886080ul);          // 16 MB [alias: Ah+Al pre-attn]
    float*  cT    = (float*)(wb + 100663296ul);         // 2 MB  [alias: C_hi+C_lo]
    float*  cnm   = (float*)(wb + 102760448ul);         // 16 KB
    ushort_t* Qu_hi = (ushort_t*)(wb + 102776832ul);    // 8 MB  [alias: Wtq pre-split]
    ushort_t* Qu_lo = (ushort_t*)(wb + 111165440ul);    // 8 MB  [alias: Wtvg pre-split]
    ushort_t* Qv_hi = (ushort_t*)(wb + 119554048ul);    // 8 MB  [alias: Wtres post-attn]
    ushort_t* K_lo  = (ushort_t*)(wb + 136331264ul);    // 16 MB
    ushort_t* R_hi  = (ushort_t*)(wb + 153108480ul);    // 2 MB
    float*  cbias   = (float*)(wb + 157302784ul);       // 128 KB

    ushort_t* K_hi  = (ushort_t*)x_t;
    ushort_t* Vt_hi = (ushort_t*)kbuf;
    ushort_t* Vt_lo = (ushort_t*)qbuf;
    ushort_t* At_hi = (ushort_t*)vbuf;
    ushort_t* At_lo = (ushort_t*)(wb + 50331648ul + 8388608ul);
    ushort_t* C_hi  = (ushort_t*)cT;
    ushort_t* C_lo  = (ushort_t*)(wb + 100663296ul + 1048576ul);

    // aliased bf16 GEMM operands
    ushort_t* Ah      = (ushort_t*)wvg;                          // 8 MB
    ushort_t* Al      = (ushort_t*)(wb + 83886080ul + 8388608ul);
    ushort_t* Wtq_hi  = (ushort_t*)Qu_hi;                        // 2 MB
    ushort_t* Wtq_lo  = (ushort_t*)(wb + 102776832ul + 2097152ul);
    ushort_t* Wtvg_hi = (ushort_t*)Qu_lo;                        // 4 MB
    ushort_t* Wtvg_lo = (ushort_t*)(wb + 111165440ul + 4194304ul);
    ushort_t* Wtres_hi = (ushort_t*)Qv_hi;                       // 2 MB
    ushort_t* Wtres_lo = (ushort_t*)(wb + 119554048ul + 2097152ul);
    ushort_t* Awh     = (ushort_t*)x_t;                          // 8 MB (post-attn)
    ushort_t* Awl     = (ushort_t*)(wb + 8388608ul);

    // 1) input LN
    ln_dm_kernel<<<4096, 256, 0, stream>>>(x_in, x_t);
    // 2) split activations + weights for bf16 GEMMs
    split_plain_kernel<<<16384, 256, 0, stream>>>(x_t, Ah, Al);
    wtsplit_kernel<<<dim3(16, 16), 256, 0, stream>>>(W_q, 1024, 0, Wtq_hi, Wtq_lo);
    wtsplit_kernel<<<dim3(32, 16), 256, 0, stream>>>(W_kvg, 3072, 1024, Wtvg_hi, Wtvg_lo);
    // 3) GEMMs: q (bf16), v+g (bf16), k (fp32 — argmin-critical)
    gemm_bf16_kernel<<<dim3(8, 32), 256, 0, stream>>>(Ah, Al, Wtq_hi, Wtq_lo, 0, qbuf, nullptr);
    gemm_bf16_kernel<<<dim3(16, 32), 256, 0, stream>>>(Ah, Al, Wtvg_hi, Wtvg_lo, 1, vbuf, gbuf);
    gemm_kernel<<<dim3(16, 64), 256, 0, stream>>>(x_t, W_kvg, 3072, 0, kbuf, nullptr, nullptr);
    // 4) LN(q), LN(k); VQ
    ln128_kernel<<<16384, 256, 0, stream>>>(qbuf, kbuf);
    cbt_kernel<<<2048, 256, 0, stream>>>(cbk, cT);
    cnorm_kernel<<<1024, 256, 0, stream>>>(cbk, cnm);
    vq_kernel<<<2048, 256, 0, stream>>>(kbuf, cT, cnm, cbk);
    // 5) attention preps
    split_q_kernel<<<16384, 256, 0, stream>>>(qbuf, x_u, x_v, Qu_hi, Qu_lo, Qv_hi);
    split_koff_kernel<<<16384, 256, 0, stream>>>(xl_k, K_hi, K_lo, 0);
    split_koff_kernel<<<16384, 256, 0, stream>>>(kbuf, K_hi, K_lo, 512);
    split_plain_kernel<<<2048, 256, 0, stream>>>(cbk, C_hi, C_lo);
    cvt_hi_kernel<<<4096, 256, 0, stream>>>(xl_r, R_hi);
    vtsplit_kernel<<<dim3(64, 16), 256, 0, stream>>>(xl_v, vbuf, Vt_hi, Vt_lo, 1024);
    vtsplit_kernel<<<dim3(64, 8), 256, 0, stream>>>(agg_u, agg_u, At_hi, At_lo, 512);
    cbias_kernel<<<128, 256, 0, stream>>>(agg_l, cbias);
    // 6) split-K fused attention
    attn4_kernel<<<1024, 256, 0, stream>>>(Qu_hi, Qu_lo, Qv_hi, K_hi, K_lo, C_hi, C_lo,
                                           Vt_hi, Vt_lo, At_hi, At_lo, R_hi,
                                           cbias, gbuf, wvg);
    // 7) output GEMM (bf16)
    split_plain_kernel<<<16384, 256, 0, stream>>>(wvg, Awh, Awl);
    wtsplit_kernel<<<dim3(16, 16), 256, 0, stream>>>(W_res, 1024, 0, Wtres_hi, Wtres_lo);
    gemm_bf16_kernel<<<dim3(8, 32), 256, 0, stream>>>(Awh, Awl, Wtres_hi, Wtres_lo, 2, out, nullptr);
}

// Round 5
// 930.818 us; speedup vs baseline: 3.3158x; 1.1124x over previous
//
#include <hip/hip_runtime.h>

#define INF30 1e30f
#define INV_TAU 0.08838834764831845f

typedef unsigned short ushort_t;
typedef __attribute__((ext_vector_type(8))) short bf16x8;
typedef __attribute__((ext_vector_type(4))) float f32x4;
typedef __attribute__((ext_vector_type(8))) unsigned short us8;

__device__ __forceinline__ float4 ld4(const float* p) { return *(const float4*)p; }

__device__ __forceinline__ unsigned short bf16_rne(float x) {
    unsigned int u = __float_as_uint(x);
    unsigned int r = u + 0x7fffu + ((u >> 16) & 1u);
    return (unsigned short)(r >> 16);
}
__device__ __forceinline__ float bf16_tof(unsigned short h) {
    return __uint_as_float(((unsigned int)h) << 16);
}
__device__ __forceinline__ bf16x8 ldb8(const ushort_t* p) { return *(const bf16x8*)p; }

#define MFMA16(a, b, c) __builtin_amdgcn_mfma_f32_16x16x32_bf16((a), (b), (c), 0, 0, 0)

// ---------------- LayerNorm over DM=1024 ----------------
__global__ __launch_bounds__(256) void ln_dm_kernel(const float* __restrict__ x, float* __restrict__ y) {
    size_t row = blockIdx.x;
    const float4* xr = (const float4*)(x + row * 1024);
    float4 v = xr[threadIdx.x];
    float s  = v.x + v.y + v.z + v.w;
    float ss = v.x*v.x + v.y*v.y + v.z*v.z + v.w*v.w;
#pragma unroll
    for (int off = 32; off > 0; off >>= 1) {
        s  += __shfl_down(s, off);
        ss += __shfl_down(ss, off);
    }
    __shared__ float rs[4], rss[4];
    int wv = threadIdx.x >> 6, ln = threadIdx.x & 63;
    if (ln == 0) { rs[wv] = s; rss[wv] = ss; }
    __syncthreads();
    s  = rs[0] + rs[1] + rs[2] + rs[3];
    ss = rss[0] + rss[1] + rss[2] + rss[3];
    float mu  = s * (1.0f/1024.0f);
    float var = ss * (1.0f/1024.0f) - mu*mu;
    float r = rsqrtf(var + 1e-6f);
    float4 o;
    o.x = (v.x - mu) * r; o.y = (v.y - mu) * r; o.z = (v.z - mu) * r; o.w = (v.w - mu) * r;
    ((float4*)(y + row * 1024))[threadIdx.x] = o;
}

// ---------------- fp32 tiled GEMM (k-columns only: argmin-critical path) ----------------
__global__ __launch_bounds__(256) void gemm_kernel(const float* __restrict__ A, const float* __restrict__ W,
                                                   int N, int mode,
                                                   float* __restrict__ o0, float* __restrict__ o1,
                                                   float* __restrict__ o2) {
    __shared__ float As[16][64];
    __shared__ float Bs[16][64];
    int t = threadIdx.x;
    int col0 = blockIdx.x << 6;
    int row0 = blockIdx.y << 6;
    int tx = t & 15, ty = t >> 4;
    int arow = t >> 2, akq = t & 3;
    int bkr = t >> 4, bcq = t & 15;
    const float* Ap = A + (size_t)(row0 + arow) * 1024 + akq * 4;
    const float* Wp = W + (size_t)bkr * N + col0 + bcq * 4;
    float acc[4][4];
#pragma unroll
    for (int i = 0; i < 4; ++i)
#pragma unroll
        for (int j = 0; j < 4; ++j) acc[i][j] = 0.0f;

    for (int kt = 0; kt < 64; ++kt) {
        float4 a4 = ld4(Ap + kt * 16);
        float4 b4 = ld4(Wp + (size_t)kt * 16 * N);
        __syncthreads();
        As[akq*4+0][arow] = a4.x;
        As[akq*4+1][arow] = a4.y;
        As[akq*4+2][arow] = a4.z;
        As[akq*4+3][arow] = a4.w;
        *(float4*)&Bs[bkr][bcq*4] = b4;
        __syncthreads();
#pragma unroll
        for (int kk = 0; kk < 16; ++kk) {
            float4 av = *(float4*)&As[kk][ty*4];
            float4 bv = *(float4*)&Bs[kk][tx*4];
            acc[0][0] += av.x*bv.x; acc[0][1] += av.x*bv.y; acc[0][2] += av.x*bv.z; acc[0][3] += av.x*bv.w;
            acc[1][0] += av.y*bv.x; acc[1][1] += av.y*bv.y; acc[1][2] += av.y*bv.z; acc[1][3] += av.y*bv.w;
            acc[2][0] += av.z*bv.x; acc[2][1] += av.z*bv.y; acc[2][2] += av.z*bv.z; acc[2][3] += av.z*bv.w;
            acc[3][0] += av.w*bv.x; acc[3][1] += av.w*bv.y; acc[3][2] += av.w*bv.z; acc[3][3] += av.w*bv.w;
        }
    }

#pragma unroll
    for (int i = 0; i < 4; ++i) {
        int rr = row0 + ty*4 + i;
        int b = rr >> 9, l = rr & 511;
#pragma unroll
        for (int j = 0; j < 4; ++j) {
            int cc = col0 + tx*4 + j;
            float vv = acc[i][j];
            if (mode == 0) {
                o0[((size_t)((b<<3) + (cc>>7)) * 512 + l) * 128 + (cc & 127)] = vv;
            } else if (mode == 1) {
                if (cc < 1024) {
                    o0[((size_t)((b<<3) + (cc>>7)) * 512 + l) * 128 + (cc & 127)] = vv;
                } else if (cc < 2048) {
                    int c2 = cc - 1024;
                    o1[((size_t)((b<<3) + (c2>>7)) * 512 + l) * 128 + (c2 & 127)] = vv;
                } else {
                    o2[(size_t)rr * 1024 + (cc - 2048)] = vv / (1.0f + __expf(-vv));
                }
            } else {
                o0[(size_t)rr * 1024 + cc] = vv;
            }
        }
    }
}

// ---------------- weight transpose + bf16 hi/lo split ----------------
__global__ __launch_bounds__(256) void wtsplit_kernel(const float* __restrict__ W, int Ntot, int c0,
                                                      ushort_t* __restrict__ th, ushort_t* __restrict__ tl) {
    __shared__ float T[64][68];
    int n0 = blockIdx.x << 6, k0 = blockIdx.y << 6, t = threadIdx.x;
    for (int i = t; i < 1024; i += 256) {
        int kk = i >> 4, nn4 = (i & 15) << 2;
        *(float4*)&T[kk][nn4] = ld4(W + (size_t)(k0 + kk) * Ntot + c0 + n0 + nn4);
    }
    __syncthreads();
    for (int i = t; i < 512; i += 256) {
        int nn = i >> 3, kc = (i & 7) << 3;
        us8 h8, l8;
#pragma unroll
        for (int j = 0; j < 8; ++j) {
            float x = T[kc + j][nn];
            unsigned short hh = bf16_rne(x);
            h8[j] = hh; l8[j] = bf16_rne(x - bf16_tof(hh));
        }
        size_t off = (size_t)(n0 + nn) * 1024 + k0 + kc;
        *(us8*)(th + off) = h8;
        *(us8*)(tl + off) = l8;
    }
}

// ---------------- bf16 3-term split GEMM ----------------
#define GSTRIDE 40
__global__ __launch_bounds__(256) void gemm_bf16_kernel(
        const ushort_t* __restrict__ Ah, const ushort_t* __restrict__ Al,
        const ushort_t* __restrict__ Bth, const ushort_t* __restrict__ Btl,
        int mode, float* __restrict__ o0, float* __restrict__ o1) {
    __shared__ ushort_t LA[2][128 * GSTRIDE];
    __shared__ ushort_t LB[2][128 * GSTRIDE];
    int t = threadIdx.x;
    int col0 = blockIdx.x << 7, row0 = blockIdx.y << 7;
    int wvid = t >> 6, ln = t & 63;
    int lcol = ln & 15, quad = ln >> 4;
    int qm = wvid >> 1, qn = wvid & 1;

    f32x4 C[4][4];
#pragma unroll
    for (int i = 0; i < 4; ++i)
#pragma unroll
        for (int j = 0; j < 4; ++j) C[i][j] = (f32x4){0.f, 0.f, 0.f, 0.f};

    for (int k0 = 0; k0 < 1024; k0 += 32) {
        us8 ra[2][2], rb[2][2];
#pragma unroll
        for (int v = 0; v < 2; ++v) {
            int cid = t + 256 * v;
            int row = cid >> 2, ch = cid & 3;
            size_t ga = (size_t)(row0 + row) * 1024 + k0 + ch * 8;
            size_t gb = (size_t)(col0 + row) * 1024 + k0 + ch * 8;
            ra[v][0] = *(const us8*)(Ah + ga);
            ra[v][1] = *(const us8*)(Al + ga);
            rb[v][0] = *(const us8*)(Bth + gb);
            rb[v][1] = *(const us8*)(Btl + gb);
        }
        __syncthreads();
#pragma unroll
        for (int v = 0; v < 2; ++v) {
            int cid = t + 256 * v;
            int row = cid >> 2, ch = cid & 3;
            *(us8*)&LA[0][row * GSTRIDE + ch * 8] = ra[v][0];
            *(us8*)&LA[1][row * GSTRIDE + ch * 8] = ra[v][1];
            *(us8*)&LB[0][row * GSTRIDE + ch * 8] = rb[v][0];
            *(us8*)&LB[1][row * GSTRIDE + ch * 8] = rb[v][1];
        }
        __syncthreads();
        bf16x8 afh[4], afl[4], bfh[4], bfl[4];
#pragma unroll
        for (int i = 0; i < 4; ++i) {
            int r = qm * 64 + i * 16 + lcol;
            afh[i] = *(const bf16x8*)&LA[0][r * GSTRIDE + quad * 8];
            afl[i] = *(const bf16x8*)&LA[1][r * GSTRIDE + quad * 8];
            int c = qn * 64 + i * 16 + lcol;
            bfh[i] = *(const bf16x8*)&LB[0][c * GSTRIDE + quad * 8];
            bfl[i] = *(const bf16x8*)&LB[1][c * GSTRIDE + quad * 8];
        }
#pragma unroll
        for (int i = 0; i < 4; ++i)
#pragma unroll
            for (int j = 0; j < 4; ++j) {
                C[i][j] = MFMA16(afh[i], bfh[j], C[i][j]);
                C[i][j] = MFMA16(afl[i], bfh[j], C[i][j]);
                C[i][j] = MFMA16(afh[i], bfl[j], C[i][j]);
            }
    }

#pragma unroll
    for (int i = 0; i < 4; ++i) {
#pragma unroll
        for (int r = 0; r < 4; ++r) {
            int rr = row0 + qm * 64 + 16 * i + quad * 4 + r;
            int b = rr >> 9, l = rr & 511;
#pragma unroll
            for (int j = 0; j < 4; ++j) {
                int cc = col0 + qn * 64 + 16 * j + lcol;
                float vv = C[i][j][r];
                if (mode == 0) {
                    o0[((size_t)((b<<3) + (cc>>7)) * 512 + l) * 128 + (cc & 127)] = vv;
                } else if (mode == 1) {
                    if (cc < 1024) o0[((size_t)((b<<3) + (cc>>7)) * 512 + l) * 128 + (cc & 127)] = vv;
                    else o1[(size_t)rr * 1024 + (cc - 1024)] = vv / (1.0f + __expf(-vv));
                } else {
                    o0[(size_t)rr * 1024 + cc] = vv;
                }
            }
        }
    }
}

// ---------------- LayerNorm over last dim 128 for q and k, in place ----------------
__global__ __launch_bounds__(256) void ln128_kernel(float* __restrict__ qb, float* __restrict__ kb) {
    int wv = threadIdx.x >> 6, ln = threadIdx.x & 63;
    int gw = (blockIdx.x << 2) + wv;
    float* base = (gw < 32768) ? qb : kb;
    int row = gw & 32767;
    float2 x = *(float2*)(base + (size_t)row * 128 + (ln << 1));
    float s  = x.x + x.y;
    float ss = x.x*x.x + x.y*x.y;
#pragma unroll
    for (int m = 32; m > 0; m >>= 1) { s += __shfl_xor(s, m); ss += __shfl_xor(ss, m); }
    float mu  = s * (1.0f/128.0f);
    float var = ss * (1.0f/128.0f) - mu*mu;
    float r = rsqrtf(var + 1e-6f);
    x.x = (x.x - mu) * r; x.y = (x.y - mu) * r;
    *(float2*)(base + (size_t)row * 128 + (ln << 1)) = x;
}

// ---------------- codebook transpose + norms ----------------
__global__ __launch_bounds__(256) void cbt_kernel(const float* __restrict__ cb, float* __restrict__ cT) {
    int idx = blockIdx.x * 256 + threadIdx.x;
    int h = idx >> 16, s = (idx >> 7) & 511, d = idx & 127;
    cT[((size_t)((h << 7) + d)) * 512 + s] = cb[idx];
}

__global__ __launch_bounds__(256) void cnorm_kernel(const float* __restrict__ cb, float* __restrict__ cn) {
    int wv = threadIdx.x >> 6, ln = threadIdx.x & 63;
    int row = (blockIdx.x << 2) + wv;
    float2 x = *(const float2*)(cb + (size_t)row * 128 + (ln << 1));
    float ss = x.x*x.x + x.y*x.y;
#pragma unroll
    for (int m = 32; m > 0; m >>= 1) ss += __shfl_xor(ss, m);
    if (ln == 0) cn[row] = ss;
}

// ---------------- VQ argmin (fp32) ----------------
__global__ __launch_bounds__(256) void vq_kernel(float* __restrict__ kb, const float* __restrict__ cT,
                                                 const float* __restrict__ cn, const float* __restrict__ cb) {
    __shared__ float sK[4][4][128];
    int wv = threadIdx.x >> 6, ln = threadIdx.x & 63;
    int gw = (blockIdx.x << 2) + wv;
    int bh = gw >> 7;
    int l4 = (gw & 127) << 2;
    int h = bh & 7;
    size_t r0 = ((size_t)bh << 9) + l4;
#pragma unroll
    for (int i = 0; i < 4; ++i) {
        float2 kx = *(const float2*)(kb + (r0 + i) * 128 + (ln << 1));
        sK[wv][i][(ln<<1)]   = kx.x;
        sK[wv][i][(ln<<1)+1] = kx.y;
    }
    __syncthreads();
    const float* ct = cT + ((size_t)h << 7) * 512;
    int s0 = ln << 3;
    float dt[4][8];
#pragma unroll
    for (int i = 0; i < 4; ++i)
#pragma unroll
        for (int j = 0; j < 8; ++j) dt[i][j] = 0.0f;

    for (int dc = 0; dc < 4; ++dc) {
        float ch[4][8];
#pragma unroll
        for (int i = 0; i < 4; ++i)
#pragma unroll
            for (int j = 0; j < 8; ++j) ch[i][j] = 0.0f;
#pragma unroll 4
        for (int d = dc * 32; d < dc * 32 + 32; ++d) {
            float4 c0 = ld4(ct + (size_t)d * 512 + s0);
            float4 c1 = ld4(ct + (size_t)d * 512 + s0 + 4);
#pragma unroll
            for (int i = 0; i < 4; ++i) {
                float kd = sK[wv][i][d];
                ch[i][0] += kd * c0.x; ch[i][1] += kd * c0.y; ch[i][2] += kd * c0.z; ch[i][3] += kd * c0.w;
                ch[i][4] += kd * c1.x; ch[i][5] += kd * c1.y; ch[i][6] += kd * c1.z; ch[i][7] += kd * c1.w;
            }
        }
#pragma unroll
        for (int i = 0; i < 4; ++i)
#pragma unroll
            for (int j = 0; j < 8; ++j) dt[i][j] += ch[i][j];
    }
    const float* cnh = cn + (h << 9);
#pragma unroll
    for (int i = 0; i < 4; ++i) {
        float bestv = cnh[s0] - 2.0f * dt[i][0];
        int bestz = s0;
#pragma unroll
        for (int j = 1; j < 8; ++j) {
            float scv = cnh[s0 + j] - 2.0f * dt[i][j];
            if (scv < bestv) { bestv = scv; bestz = s0 + j; }
        }
#pragma unroll
        for (int m = 32; m > 0; m >>= 1) {
            float ov = __shfl_xor(bestv, m);
            int   oz = __shfl_xor(bestz, m);
            if (ov < bestv || (ov == bestv && oz < bestz)) { bestv = ov; bestz = oz; }
        }
        float2 cz = *(const float2*)(cb + ((size_t)(h << 9) + bestz) * 128 + (ln << 1));
        *(float2*)(kb + (r0 + i) * 128 + (ln << 1)) = cz;
    }
}

// ---------------- prep kernels ----------------
__global__ __launch_bounds__(256) void split_q_kernel(const float* __restrict__ q,
        const float* __restrict__ xu, const float* __restrict__ xv,
        ushort_t* __restrict__ quh, ushort_t* __restrict__ qul,
        ushort_t* __restrict__ qvh) {
    int idx = blockIdx.x * 256 + threadIdx.x;
    int d = idx & 127;
    int h = (idx >> 16) & 7;
    float qv = q[idx];
    float a = qv + xu[(h << 7) + d];
    unsigned short ah = bf16_rne(a);
    quh[idx] = ah; qul[idx] = bf16_rne(a - bf16_tof(ah));
    float b = qv + xv[(h << 7) + d];
    qvh[idx] = bf16_rne(b);
}

__global__ __launch_bounds__(256) void split_plain_kernel(const float* __restrict__ src,
        ushort_t* __restrict__ hi, ushort_t* __restrict__ lo) {
    int idx = blockIdx.x * 256 + threadIdx.x;
    float x = src[idx];
    unsigned short h = bf16_rne(x);
    hi[idx] = h; lo[idx] = bf16_rne(x - bf16_tof(h));
}

__global__ __launch_bounds__(256) void cvt_hi_kernel(const float* __restrict__ src,
        ushort_t* __restrict__ hi) {
    int idx = blockIdx.x * 256 + threadIdx.x;
    hi[idx] = bf16_rne(src[idx]);
}

__global__ __launch_bounds__(256) void split_koff_kernel(const float* __restrict__ src,
        ushort_t* __restrict__ hi, ushort_t* __restrict__ lo, int rowoff) {
    int idx = blockIdx.x * 256 + threadIdx.x;
    int bh = idx >> 16, rem = idx & 65535;
    size_t dst = ((size_t)bh << 17) + ((size_t)rowoff << 7) + rem;
    float x = src[idx];
    unsigned short h = bf16_rne(x);
    hi[dst] = h; lo[dst] = bf16_rne(x - bf16_tof(h));
}

__global__ __launch_bounds__(256) void vtsplit_kernel(const float* __restrict__ srcA,
        const float* __restrict__ srcB, ushort_t* __restrict__ hi, ushort_t* __restrict__ lo, int NK) {
    __shared__ float T[64][132];
    int bh = blockIdx.x, kt = blockIdx.y, t = threadIdx.x;
    for (int i = t; i < 2048; i += 256) {
        int r = i >> 5, c4 = (i & 31) << 2;
        int key = (kt << 6) + r;
        const float* s = (key < 512) ? (srcA + ((size_t)bh * 512 + key) * 128 + c4)
                                     : (srcB + ((size_t)bh * 512 + (key - 512)) * 128 + c4);
        *(float4*)&T[r][c4] = ld4(s);
    }
    __syncthreads();
    for (int i = t; i < 1024; i += 256) {
        int vc = i >> 3, kk = (i & 7) << 3;
        us8 h8, l8;
#pragma unroll
        for (int j = 0; j < 8; ++j) {
            float x = T[kk + j][vc];
            unsigned short hh = bf16_rne(x);
            h8[j] = hh; l8[j] = bf16_rne(x - bf16_tof(hh));
        }
        size_t off = ((size_t)bh * 128 + vc) * NK + (kt << 6) + kk;
        *(us8*)(hi + off) = h8;
        *(us8*)(lo + off) = l8;
    }
}

__global__ __launch_bounds__(256) void cbias_kernel(const float* __restrict__ al, float* __restrict__ cb) {
    int idx = blockIdx.x * 256 + threadIdx.x;
    float v = al[idx];
    cb[idx] = (v > 0.0f) ? __logf(fmaxf(v, 1e-30f)) : -INF30;
}

// ---------------- attn5: XCD-swizzled, 2 q-tiles/wave, split-K, shared K/V frags ----------------
// 512 blocks x 4 waves. bh = 8*(idx>>3) + (blk&7) pins all 8 blocks of a bh to one XCD.
// Wave pair (wp) owns q-tile pair {j, 31-j} (constant total causal work); split point half=20
// equalizes weighted work (seg0/1 iters count double: both tiles active).
#define PSTR 40
__global__ __launch_bounds__(256, 2) void attn5_kernel(
        const ushort_t* __restrict__ Qu_hi, const ushort_t* __restrict__ Qu_lo,
        const ushort_t* __restrict__ Qv_hi,
        const ushort_t* __restrict__ K_hi,  const ushort_t* __restrict__ K_lo,
        const ushort_t* __restrict__ C_hi,  const ushort_t* __restrict__ C_lo,
        const ushort_t* __restrict__ Vt_hi, const ushort_t* __restrict__ Vt_lo,
        const ushort_t* __restrict__ At_hi, const ushort_t* __restrict__ At_lo,
        const ushort_t* __restrict__ R_hi,
        const float* __restrict__ cbias, const float* __restrict__ gbuf,
        float* __restrict__ wvg) {
    __shared__ __align__(16) ushort_t Phs[4][2][16 * PSTR];
    __shared__ __align__(16) ushort_t Pls[4][2][16 * PSTR];
    __shared__ float Oc[4][16 * 132];
    __shared__ float mc[4][16], lc[4][16];

    int t = threadIdx.x;
    int wvid = t >> 6, ln = t & 63;
    int col = ln & 15, quad = ln >> 4;
    int blk = blockIdx.x;
    int xcd = blk & 7, idx = blk >> 3;
    int bh = ((idx >> 3) << 3) + xcd;
    int sub = idx & 7;
    int wp = wvid >> 1, q = wvid & 1;
    int pairj = (sub << 1) + wp;
    int l0[2];
    l0[0] = pairj << 4;
    l0[1] = (31 - pairj) << 4;
    int h = bh & 7, b = bh >> 3;

    // persistent Qu A-frags for both tiles
    bf16x8 quh[2][4], qul[2][4];
#pragma unroll
    for (int tt = 0; tt < 2; ++tt) {
        size_t base = ((size_t)bh * 512 + l0[tt] + col) * 128 + quad * 8;
#pragma unroll
        for (int s = 0; s < 4; ++s) {
            quh[tt][s] = ldb8(Qu_hi + base + 32 * s);
            qul[tt][s] = ldb8(Qu_lo + base + 32 * s);
        }
    }

    f32x4 O[2][8];
#pragma unroll
    for (int tt = 0; tt < 2; ++tt)
#pragma unroll
        for (int u = 0; u < 8; ++u) O[tt][u] = (f32x4){0.f, 0.f, 0.f, 0.f};
    float mrun[2][4], lrun[2][4];
#pragma unroll
    for (int tt = 0; tt < 2; ++tt)
#pragma unroll
        for (int r = 0; r < 4; ++r) { mrun[tt][r] = -INF30; lrun[tt][r] = 0.0f; }

    int nt2A = (l0[0] + 47) >> 5;
    int nt2B = (l0[1] + 47) >> 5;
    int Tt = 32 + nt2B;
    int ti0 = q ? 20 : 0;
    int ti1 = q ? Tt : 20;

    for (int ti = ti0; ti < ti1; ++ti) {
        int seg, w0;
        if (ti < 16)      { seg = 0; w0 = ti << 5; }
        else if (ti < 32) { seg = 1; w0 = (ti - 16) << 5; }
        else              { seg = 2; w0 = (ti - 32) << 5; }
        bool actA = (seg != 2) || ((ti - 32) < nt2A);

        // ---- rel G tiles in registers (seg 0/2); qv frags reloaded from L2 ----
        f32x4 Gacc[2][3];
        if (seg != 1) {
#pragma unroll
            for (int tt = 0; tt < 2; ++tt) {
                if (tt == 0 && !actA) continue;
                size_t qb_ = ((size_t)bh * 512 + l0[tt] + col) * 128 + quad * 8;
                bf16x8 qv0 = ldb8(Qv_hi + qb_);
                bf16x8 qv1 = ldb8(Qv_hi + qb_ + 32);
                bf16x8 qv2 = ldb8(Qv_hi + qb_ + 64);
                bf16x8 qv3 = ldb8(Qv_hi + qb_ + 96);
                int jt0 = ((seg == 0) ? w0 : (512 + w0)) + 496 - l0[tt];
#pragma unroll
                for (int u = 0; u < 3; ++u) {
                    int j = jt0 + 16 * u + col;
                    j = (j > 1023) ? 1023 : j;
                    const ushort_t* rp = R_hi + ((size_t)(h << 10) + j) * 128 + quad * 8;
                    f32x4 acc = (f32x4){0.f, 0.f, 0.f, 0.f};
                    acc = MFMA16(qv0, ldb8(rp), acc);
                    acc = MFMA16(qv1, ldb8(rp + 32), acc);
                    acc = MFMA16(qv2, ldb8(rp + 64), acc);
                    acc = MFMA16(qv3, ldb8(rp + 96), acc);
                    Gacc[tt][u] = acc;
                }
            }
        }

        // ---- shared K frags + scores for both tiles ----
        const ushort_t *khb, *klb;
        if (seg == 0)      { khb = K_hi + ((size_t)bh * 1024 + w0) * 128;
                             klb = K_lo + ((size_t)bh * 1024 + w0) * 128; }
        else if (seg == 1) { khb = C_hi + ((size_t)(h << 9) + w0) * 128;
                             klb = C_lo + ((size_t)(h << 9) + w0) * 128; }
        else               { khb = K_hi + ((size_t)bh * 1024 + 512 + w0) * 128;
                             klb = K_lo + ((size_t)bh * 1024 + 512 + w0) * 128; }
        f32x4 S[2][2];
#pragma unroll
        for (int t2 = 0; t2 < 2; ++t2) {
            const ushort_t* kph = khb + (size_t)(16 * t2 + col) * 128 + quad * 8;
            const ushort_t* kpl = klb + (size_t)(16 * t2 + col) * 128 + quad * 8;
            bf16x8 bhf[4], blf[4];
#pragma unroll
            for (int s = 0; s < 4; ++s) { bhf[s] = ldb8(kph + 32 * s); blf[s] = ldb8(kpl + 32 * s); }
#pragma unroll
            for (int tt = 0; tt < 2; ++tt) {
                if (tt == 0 && !actA) continue;
                f32x4 acc = (f32x4){0.f, 0.f, 0.f, 0.f};
#pragma unroll
                for (int s = 0; s < 4; ++s) {
                    acc = MFMA16(quh[tt][s], bhf[s], acc);
                    acc = MFMA16(qul[tt][s], bhf[s], acc);
                    acc = MFMA16(quh[tt][s], blf[s], acc);
                }
                S[tt][t2] = acc;
            }
        }

        // ---- fixup + online softmax + P frags per tile ----
        float bias0 = 0.f, bias1 = 0.f;
        if (seg == 1) {
            bias0 = cbias[(size_t)(bh << 9) + w0 + col];
            bias1 = cbias[(size_t)(bh << 9) + w0 + 16 + col];
        }
        bf16x8 pah[2], pal[2];
#pragma unroll
        for (int tt = 0; tt < 2; ++tt) {
            if (tt == 0 && !actA) continue;
            ushort_t* Ph = Phs[wvid][tt];
            ushort_t* Pl = Pls[wvid][tt];
#pragma unroll
            for (int t2 = 0; t2 < 2; ++t2) {
#pragma unroll
                for (int r = 0; r < 4; ++r) {
                    int row = 4 * quad + r;
                    float sv = S[tt][t2][r];
                    if (seg != 1) {
                        int d = col + 15 - row;
                        int src = quad * 16 + (d & 15);
                        float g0 = __shfl(Gacc[tt][t2][r], src);
                        float g1 = __shfl(Gacc[tt][t2 + 1][r], src);
                        float gv = (d >= 16) ? g1 : g0;
                        sv = (sv + gv) * INV_TAU;
                        if (seg == 2 && (w0 + 16 * t2 + col > l0[tt] + row)) sv = -INF30;
                    } else {
                        sv = sv * INV_TAU + ((t2 == 0) ? bias0 : bias1);
                    }
                    S[tt][t2][r] = sv;
                }
            }
#pragma unroll
            for (int r = 0; r < 4; ++r) {
                float mv = fmaxf(S[tt][0][r], S[tt][1][r]);
#pragma unroll
                for (int m = 8; m > 0; m >>= 1) mv = fmaxf(mv, __shfl_xor(mv, m));
                float mnew = fmaxf(mrun[tt][r], mv);
                float alpha = __expf(mrun[tt][r] - mnew);
                mrun[tt][r] = mnew;
                float p0 = __expf(S[tt][0][r] - mnew);
                float p1 = __expf(S[tt][1][r] - mnew);
                float ps = p0 + p1;
#pragma unroll
                for (int m = 8; m > 0; m >>= 1) ps += __shfl_xor(ps, m);
                lrun[tt][r] = lrun[tt][r] * alpha + ps;
#pragma unroll
                for (int u = 0; u < 8; ++u) O[tt][u][r] *= alpha;
                int row = 4 * quad + r;
                unsigned short h0 = bf16_rne(p0);
                Ph[row * PSTR + col] = h0;
                Pl[row * PSTR + col] = bf16_rne(p0 - bf16_tof(h0));
                unsigned short h1 = bf16_rne(p1);
                Ph[row * PSTR + 16 + col] = h1;
                Pl[row * PSTR + 16 + col] = bf16_rne(p1 - bf16_tof(h1));
            }
            pah[tt] = *(const bf16x8*)&Ph[col * PSTR + quad * 8];
            pal[tt] = *(const bf16x8*)&Pl[col * PSTR + quad * 8];
        }

        // ---- PV with shared V frags ----
        const ushort_t *vh, *vl;
        size_t vstr;
        int wbase;
        if (seg == 0)      { vh = Vt_hi + ((size_t)bh << 17); vl = Vt_lo + ((size_t)bh << 17); vstr = 1024; wbase = w0; }
        else if (seg == 1) { vh = At_hi + ((size_t)bh << 16); vl = At_lo + ((size_t)bh << 16); vstr = 512;  wbase = w0; }
        else               { vh = Vt_hi + ((size_t)bh << 17); vl = Vt_lo + ((size_t)bh << 17); vstr = 1024; wbase = 512 + w0; }
#pragma unroll
        for (int u = 0; u < 8; ++u) {
            int vcol = 16 * u + col;
            bf16x8 vbh = ldb8(vh + (size_t)vcol * vstr + wbase + quad * 8);
            bf16x8 vbl = ldb8(vl + (size_t)vcol * vstr + wbase + quad * 8);
#pragma unroll
            for (int tt = 0; tt < 2; ++tt) {
                if (tt == 0 && !actA) continue;
                O[tt][u] = MFMA16(pah[tt], vbh, O[tt][u]);
                O[tt][u] = MFMA16(pal[tt], vbh, O[tt][u]);
                O[tt][u] = MFMA16(pah[tt], vbl, O[tt][u]);
            }
        }
    }

    // ---- split-K combine (one barrier) ----
    if (q) {
#pragma unroll
        for (int tt = 0; tt < 2; ++tt) {
            int sid = wp * 2 + tt;
#pragma unroll
            for (int u = 0; u < 8; ++u)
#pragma unroll
                for (int r = 0; r < 4; ++r)
                    Oc[sid][(quad * 4 + r) * 132 + 16 * u + col] = O[tt][u][r];
            if (col == 0) {
#pragma unroll
                for (int r = 0; r < 4; ++r) {
                    mc[sid][quad * 4 + r] = mrun[tt][r];
                    lc[sid][quad * 4 + r] = lrun[tt][r];
                }
            }
        }
    }
    __syncthreads();
    if (!q) {
#pragma unroll
        for (int tt = 0; tt < 2; ++tt) {
            int sid = wp * 2 + tt;
#pragma unroll
            for (int r = 0; r < 4; ++r) {
                int row = quad * 4 + r;
                float m1 = mc[sid][row], l1 = lc[sid][row];
                float mm = fmaxf(mrun[tt][r], m1);
                float a0 = __expf(mrun[tt][r] - mm);
                float a1 = __expf(m1 - mm);
                float linv = 1.0f / (lrun[tt][r] * a0 + l1 * a1);
#pragma unroll
                for (int u = 0; u < 8; ++u) {
                    size_t gi = ((size_t)b * 512 + l0[tt] + row) * 1024 + (h << 7) + 16 * u + col;
                    float val = (O[tt][u][r] * a0 + Oc[sid][row * 132 + 16 * u + col] * a1) * linv;
                    wvg[gi] = val * gbuf[gi];
                }
            }
        }
    }
}

extern "C" void kernel_launch(void* const* d_in, const int* in_sizes, int n_in,
                              void* d_out, int out_size, void* d_ws, size_t ws_size,
                              hipStream_t stream) {
    const float* x_in  = (const float*)d_in[0];
    const float* xl_k  = (const float*)d_in[2];
    const float* xl_v  = (const float*)d_in[3];
    const float* agg_u = (const float*)d_in[4];
    const float* agg_l = (const float*)d_in[5];
    const float* W_q   = (const float*)d_in[6];
    const float* W_kvg = (const float*)d_in[7];
    const float* W_res = (const float*)d_in[8];
    const float* x_u   = (const float*)d_in[9];
    const float* x_v   = (const float*)d_in[10];
    const float* xl_r  = (const float*)d_in[11];
    const float* cbk   = (const float*)d_in[12];
    float* out = (float*)d_out;
    char* wb = (char*)d_ws;

    float*  x_t   = (float*)(wb);                       // 16 MB [alias: K_hi; later Awh/Awl]
    float*  qbuf  = (float*)(wb + 16777216ul);          // 16 MB [alias: Vt_lo]
    float*  kbuf  = (float*)(wb + 33554432ul);          // 16 MB [alias: Vt_hi]
    float*  vbuf  = (float*)(wb + 50331648ul);          // 16 MB [alias: At_hi+At_lo]
    float*  gbuf  = (float*)(wb + 67108864ul);          // 16 MB
    float*  wvg   = (float*)(wb + 83886080ul);          // 16 MB [alias: Ah+Al pre-attn]
    float*  cT    = (float*)(wb + 100663296ul);         // 2 MB  [alias: C_hi+C_lo]
    float*  cnm   = (float*)(wb + 102760448ul);         // 16 KB
    ushort_t* Qu_hi = (ushort_t*)(wb + 102776832ul);    // 8 MB  [alias: Wtq pre-split]
    ushort_t* Qu_lo = (ushort_t*)(wb + 111165440ul);    // 8 MB  [alias: Wtvg pre-split]
    ushort_t* Qv_hi = (ushort_t*)(wb + 119554048ul);    // 8 MB  [alias: Wtres post-attn]
    ushort_t* K_lo  = (ushort_t*)(wb + 136331264ul);    // 16 MB
    ushort_t* R_hi  = (ushort_t*)(wb + 153108480ul);    // 2 MB
    float*  cbias   = (float*)(wb + 157302784ul);       // 128 KB

    ushort_t* K_hi  = (ushort_t*)x_t;
    ushort_t* Vt_hi = (ushort_t*)kbuf;
    ushort_t* Vt_lo = (ushort_t*)qbuf;
    ushort_t* At_hi = (ushort_t*)vbuf;
    ushort_t* At_lo = (ushort_t*)(wb + 50331648ul + 8388608ul);
    ushort_t* C_hi  = (ushort_t*)cT;
    ushort_t* C_lo  = (ushort_t*)(wb + 100663296ul + 1048576ul);

    ushort_t* Ah      = (ushort_t*)wvg;
    ushort_t* Al      = (ushort_t*)(wb + 83886080ul + 8388608ul);
    ushort_t* Wtq_hi  = (ushort_t*)Qu_hi;
    ushort_t* Wtq_lo  = (ushort_t*)(wb + 102776832ul + 2097152ul);
    ushort_t* Wtvg_hi = (ushort_t*)Qu_lo;
    ushort_t* Wtvg_lo = (ushort_t*)(wb + 111165440ul + 4194304ul);
    ushort_t* Wtres_hi = (ushort_t*)Qv_hi;
    ushort_t* Wtres_lo = (ushort_t*)(wb + 119554048ul + 2097152ul);
    ushort_t* Awh     = (ushort_t*)x_t;
    ushort_t* Awl     = (ushort_t*)(wb + 8388608ul);

    // 1) input LN
    ln_dm_kernel<<<4096, 256, 0, stream>>>(x_in, x_t);
    // 2) split activations + weights for bf16 GEMMs
    split_plain_kernel<<<16384, 256, 0, stream>>>(x_t, Ah, Al);
    wtsplit_kernel<<<dim3(16, 16), 256, 0, stream>>>(W_q, 1024, 0, Wtq_hi, Wtq_lo);
    wtsplit_kernel<<<dim3(32, 16), 256, 0, stream>>>(W_kvg, 3072, 1024, Wtvg_hi, Wtvg_lo);
    // 3) GEMMs: q (bf16), v+g (bf16), k (fp32 — argmin-critical)
    gemm_bf16_kernel<<<dim3(8, 32), 256, 0, stream>>>(Ah, Al, Wtq_hi, Wtq_lo, 0, qbuf, nullptr);
    gemm_bf16_kernel<<<dim3(16, 32), 256, 0, stream>>>(Ah, Al, Wtvg_hi, Wtvg_lo, 1, vbuf, gbuf);
    gemm_kernel<<<dim3(16, 64), 256, 0, stream>>>(x_t, W_kvg, 3072, 0, kbuf, nullptr, nullptr);
    // 4) LN(q), LN(k); VQ
    ln128_kernel<<<16384, 256, 0, stream>>>(qbuf, kbuf);
    cbt_kernel<<<2048, 256, 0, stream>>>(cbk, cT);
    cnorm_kernel<<<1024, 256, 0, stream>>>(cbk, cnm);
    vq_kernel<<<2048, 256, 0, stream>>>(kbuf, cT, cnm, cbk);
    // 5) attention preps
    split_q_kernel<<<16384, 256, 0, stream>>>(qbuf, x_u, x_v, Qu_hi, Qu_lo, Qv_hi);
    split_koff_kernel<<<16384, 256, 0, stream>>>(xl_k, K_hi, K_lo, 0);
    split_koff_kernel<<<16384, 256, 0, stream>>>(kbuf, K_hi, K_lo, 512);
    split_plain_kernel<<<2048, 256, 0, stream>>>(cbk, C_hi, C_lo);
    cvt_hi_kernel<<<4096, 256, 0, stream>>>(xl_r, R_hi);
    vtsplit_kernel<<<dim3(64, 16), 256, 0, stream>>>(xl_v, vbuf, Vt_hi, Vt_lo, 1024);
    vtsplit_kernel<<<dim3(64, 8), 256, 0, stream>>>(agg_u, agg_u, At_hi, At_lo, 512);
    cbias_kernel<<<128, 256, 0, stream>>>(agg_l, cbias);
    // 6) swizzled 2-tile split-K fused attention
    attn5_kernel<<<512, 256, 0, stream>>>(Qu_hi, Qu_lo, Qv_hi, K_hi, K_lo, C_hi, C_lo,
                                          Vt_hi, Vt_lo, At_hi, At_lo, R_hi,
                                          cbias, gbuf, wvg);
    // 7) output GEMM (bf16)
    split_plain_kernel<<<16384, 256, 0, stream>>>(wvg, Awh, Awl);
    wtsplit_kernel<<<dim3(16, 16), 256, 0, stream>>>(W_res, 1024, 0, Wtres_hi, Wtres_lo);
    gemm_bf16_kernel<<<dim3(8, 32), 256, 0, stream>>>(Awh, Awl, Wtres_hi, Wtres_lo, 2, out, nullptr);
}